// Round 11
// baseline (246.758 us; speedup 1.0000x reference)
//
#include <hip/hip_runtime.h>
#include <math.h>

// DTW 2048x2048, squared-diff cost, out = sqrt(DTW[2047][2047]).
//
// FOUR-CU pipeline: 4 blocks x 4 waves (1 wave/SIMD on four CUs),
// 16 strips of 128 rows; strip g = 4*blockIdx + w; lane l owns strip rows
// 2l..2l+1 (R=2); C=2 cols/step: jA = tau0+2s-2l, jB = jA+1. CSTEP=32,
// DSKEW=160 (R9-proven pair), EXTRA=64 slack per cross-CU edge.
//
// WHY (rounds 0-10): lone-wave issue cadence ~5.3cy/VALU is the wall;
// R10 proved 2-CU scaling works (127us vs R7's 134.5, WRITE_SIZE fix
// 570KB->10.6KB). This round: (a) 4 CUs, R=2 -> ~13 ops/step; (b) kill
// per-step v_readlane+mov: ring injections come from uniform-address
// ds_read_b128 BROADCAST (8 reads/block replace 64 readlane+mov).
// Model: 2384 steps x (15x5.3+~28) ~ 255Kcy ~ 106us (from 127).
//
// Cross-CU edges (3): R10's proven recipe per edge e (strip 4e+3 ->
// 4e+4), rings as 1024-col WRAPPED buffers in d_ws (3x4KB + flags =
// 13KB <= 16KB bound proven available in R8/R10):
//   producer (b=e, w3): writes LDS ringW per step as usual; per block
//     end: lane<32 copies newly-final cols [tau0-126, tau0-95] from
//     ringW to grow_e[(c+2048)&1023] (plain stores); per block START
//     (tau0>=128): __threadfence() (covers copies thru block tau0-32,
//     vmcnt long drained) + lane0 release-store flag_e = tau0-127;
//     at tau0==TAUMAX: fence + flag_e = FLAGBIG (covers cols..2049).
//   consumer (b=e+1, w0): per block, spin-acquire flag_e >=
//     min(nt+31,2047) then lane<32 RELAXED-AGENT ATOMIC loads of
//     grow_e[(nt+lane)&1023] (stale-line-proof under wrap; prefetched a
//     block early, latency hidden), written to LDS cscr at block end;
//     inner loop reads cscr broadcast = identical to other waves.
//   Junk gating: wrapped slots hold junk only until the real col's copy
//   lands, which always precedes flag >= that col (deferred-fence
//   arithmetic); junk cols >= 2048 only flow rightward, never reaching
//   output col 2047; NaN/negative junk sorts LARGE under unsigned min3.
//   Deadlock-free: block b's w0 waits only on block b-1's w3 (acyclic);
//   all 4 blocks co-resident (grid 4 << 256 CUs). Pairs never straddle
//   the wrap: all pair base cols are even, slot 1023 is odd.
//
// Intra-block: LDS ring rows w -> w+1, broadcast reads of cols
// [tau0, tau0+31]; producer w-1 at the barrier completed tau0+128, its
// lane63 wrote cols <= tau0+33 >= tau0+31 (R9 proof). Row 0 = INFV
// (virtual row -1); seed DTW[-1][-1]=0 via b0/tid0 uBp.
//
// Guard-free INFV scheme as R7-R10 (1e30 absorbs adds; INFV-padded yB;
// OOB LDS ring writes land in pads; unsigned-bitcast min3 -> v_min3_u32).
//
// Output: strip 15 = b3/w3 (writes nothing), lane 63, row 1 = global
// row 2047, col jB = 2047 at tau0 = 2144 (TAUMAX), s = 14.

#define NLEN   2048
#define NWL    4
#define CSTEP  32
#define SPB    (CSTEP / 2)             // 16 steps/block
#define DSKEW  160
#define EXTRA  64
#define PAD    128
#define RROW   2304                    // ring row: cols -128..2175
#define YPAD   128
#define TAUMAX 2144
#define GTOT   (TAUMAX + 15 * DSKEW + 3 * EXTRA + CSTEP)   // 4768
#define RMASK  1023
#define FLAGBIG (1 << 20)
#define INFV   1e30f

typedef float f32x2 __attribute__((ext_vector_type(2)));
typedef float f32x4 __attribute__((ext_vector_type(4)));

__device__ __forceinline__ float dpp_shr1(float v, float inj) {
    int r = __builtin_amdgcn_update_dpp(
        __builtin_bit_cast(int, inj), __builtin_bit_cast(int, v),
        0x138 /*wave_shr:1*/, 0xF, 0xF, false /*lane0 keeps old=inj*/);
    return __builtin_bit_cast(float, r);
}
// 3-input min on non-negative floats via unsigned bit-pattern compare;
// umin+umin fuses to a single v_min3_u32. NaN/inf/negative sort LARGE.
__device__ __forceinline__ float min3f(float a, float b, float c) {
    unsigned ia = __builtin_bit_cast(unsigned, a);
    unsigned ib = __builtin_bit_cast(unsigned, b);
    unsigned ic = __builtin_bit_cast(unsigned, c);
    unsigned m  = __builtin_elementwise_min(
                      __builtin_elementwise_min(ia, ib), ic);
    return __builtin_bit_cast(float, m);
}
__device__ __forceinline__ void spinflag(int* flag, int target) {
    while (__hip_atomic_load(flag, __ATOMIC_ACQUIRE,
                             __HIP_MEMORY_SCOPE_AGENT) < target)
        __builtin_amdgcn_s_sleep(2);
}
__device__ __forceinline__ float gload(const float* p) {
    unsigned u = __hip_atomic_load((const unsigned*)p, __ATOMIC_RELAXED,
                                   __HIP_MEMORY_SCOPE_AGENT);
    return __builtin_bit_cast(float, u);
}

// ---------------- 4-block (4-CU) kernel ----------------
__global__ __launch_bounds__(256, 1) void dtw_kernel(const float* __restrict__ X,
                                                     const float* __restrict__ Y,
                                                     float* __restrict__ out,
                                                     float* __restrict__ ws) {
    __shared__ __align__(16) float yB[YPAD + NLEN + YPAD];
    __shared__ __align__(16) float ring[(NWL + 1) * RROW];
    __shared__ __align__(16) float cscr[32];
    float* yS = yB + YPAD;

    const int tid  = threadIdx.x;
    const int w    = tid >> 6;
    const int lane = tid & 63;
    const int b    = blockIdx.x;
    const int skew = (4 * b + w) * DSKEW + b * EXTRA;
    const bool isprod = (b < 3) & (w == 3);
    const bool iscons = (b > 0) & (w == 0);
    const bool isbot  = (b == 3) & (w == 3);

    int*   flagp = (int*)ws + 64 * b;         // producer publishes edge b
    int*   flagc = (int*)ws + 64 * (b - 1);   // consumer waits on edge b-1
    float* growp = (float*)ws + 256 + 1024 * b;
    float* growc = (float*)ws + 256 + 1024 * (b - 1);

    {   // Y into LDS middle, INFV pads on both sides
        const float4* Y4 = (const float4*)Y;
        float4* y4 = (float4*)(yB + YPAD);
        y4[tid]       = Y4[tid];
        y4[tid + 256] = Y4[tid + 256];
        if (tid < YPAD) {
            yB[tid]               = INFV;
            yB[YPAD + NLEN + tid] = INFV;
        }
    }
    for (int k = tid; k < (NWL + 1) * RROW; k += 256) ring[k] = INFV;
    __syncthreads();

    f32x2 xx0, xx1;
    {   // strip g = 4b+w rows 2*lane, 2*lane+1 -> X[512b+128w+2*lane]
        const float2 xa = *(const float2*)&X[b * 512 + w * 128 + lane * 2];
        xx0 = (f32x2){xa.x, xa.x};
        xx1 = (f32x2){xa.y, xa.y};
    }

    float pB0 = INFV, pB1 = INFV;
    float a1p = INFV;
    float uBp = (b == 0 && tid == 0) ? 0.0f : INFV;  // DTW[-1][-1]=0 seed

    const float* ringR = ring + w * RROW + PAD;
    float*       ringW = ring + (w + 1) * RROW + PAD;

    for (int gb = 0; gb < GTOT; gb += CSTEP) {
        const int tau0 = gb - skew;

        if (tau0 >= 0 && tau0 <= TAUMAX) {
            // producer: deferred flag (covers copies thru block tau0-32)
            if (isprod && tau0 >= 128) {
                __threadfence();
                if (lane == 0)
                    __hip_atomic_store(flagp, tau0 - 127, __ATOMIC_RELEASE,
                                       __HIP_MEMORY_SCOPE_AGENT);
            }

            // consumer: fill cscr (tau0==0) + prefetch next block
            float pref = 0.0f;
            const bool dopref = iscons & (tau0 + CSTEP <= TAUMAX);
            if (iscons) {
                if (tau0 == 0) {
                    spinflag(flagc, 31);
                    if (lane < 32)
                        cscr[lane] = gload(growc + ((lane + 2048) & RMASK));
                }
                if (dopref) {
                    const int nt = tau0 + CSTEP;
                    int tgt = nt + 31; if (tgt > NLEN - 1) tgt = NLEN - 1;
                    spinflag(flagc, tgt);
                    if (lane < 32)
                        pref = gload(growc + ((nt + lane + 2048) & RMASK));
                }
            }

            // broadcast ring values (uniform-address b128 reads)
            const float* rsrc = iscons ? cscr : (ringR + tau0);
            f32x4 rv[8];
            #pragma unroll
            for (int q = 0; q < 8; ++q) rv[q] = *(const f32x4*)(rsrc + 4 * q);

            // private y window: cols tau0-2l .. tau0-2l+31
            f32x2 y2[SPB];
            {
                const f32x2* yp = (const f32x2*)(yS + (tau0 - 2 * lane));
                #pragma unroll
                for (int k = 0; k < SPB; ++k) y2[k] = yp[k];
            }
            float* wp = ringW + (tau0 - 2 * lane);
            const bool isout = isbot & (lane == 63) & (tau0 == TAUMAX);

            #pragma unroll
            for (int s = 0; s < SPB; ++s) {
                const float riA = rv[(2 * s) >> 2][(2 * s) & 3];
                const float riB = rv[(2 * s + 1) >> 2][(2 * s + 1) & 3];
                const float uA  = dpp_shr1(a1p, riA);     // up for col A
                const float uB  = dpp_shr1(pB1, riB);     // up for col B
                const f32x2 yv = y2[s];
                f32x2 d0 = xx0 - yv;                      // v_pk_add_f32
                float n0A = fmaf(d0.x, d0.x, min3f(pB0, uA,  uBp));
                float n0B = fmaf(d0.y, d0.y, min3f(n0A, uB,  uA));
                f32x2 d1 = xx1 - yv;
                float n1A = fmaf(d1.x, d1.x, min3f(pB1, n0A, pB0));
                float n1B = fmaf(d1.y, d1.y, min3f(n1A, n0B, n0A));
                if (!isbot) {
                    f32x2 wv; wv.x = n1A; wv.y = n1B;
                    *(f32x2*)(wp + 2 * s) = wv;           // ds_write_b64
                }
                uBp = uB; a1p = n1A;
                pB0 = n0B; pB1 = n1B;
                if (s == 14 && isout) out[0] = sqrtf(n1B);  // col 2047
            }

            if (isprod) {
                // copy newly-final cols [tau0-126, tau0-95] to global ring
                if (lane < 32) {
                    const int c = tau0 - 126 + lane;
                    growp[(c + 2048) & RMASK] = ringW[c];
                }
                if (tau0 == TAUMAX) {                     // tail publish
                    __threadfence();
                    if (lane == 0)
                        __hip_atomic_store(flagp, FLAGBIG, __ATOMIC_RELEASE,
                                           __HIP_MEMORY_SCOPE_AGENT);
                }
            }
            if (dopref && lane < 32) cscr[lane] = pref;   // for next block
        }
        __syncthreads();
    }
}

// ---------------- fallback: R7 single-block kernel (proven 134.5us) ----------------
#define FNW    4
#define FCS    64
#define FSPB   32
#define FDSKEW 192
#define FPAD   128
#define FRROW  (FPAD + 2176)
#define FTMAX  2112
#define FGTOT  (FTMAX + (FNW - 1) * FDSKEW + FCS)   // 2752

__device__ __forceinline__ float rdlane(float v, int l) {
    return __builtin_bit_cast(float,
        __builtin_amdgcn_readlane(__builtin_bit_cast(int, v), l));
}

__global__ __launch_bounds__(256, 1) void dtw_kernel_fb(const float* __restrict__ X,
                                                        const float* __restrict__ Y,
                                                        float* __restrict__ out) {
    __shared__ __align__(16) float yB[YPAD + NLEN + YPAD];
    __shared__ float ring[(FNW + 1) * FRROW];
    float* yS = yB + YPAD;

    const int tid  = threadIdx.x;
    const int w    = tid >> 6;
    const int lane = tid & 63;

    {
        const float4* Y4 = (const float4*)Y;
        float4* y4 = (float4*)(yB + YPAD);
        y4[tid]       = Y4[tid];
        y4[tid + 256] = Y4[tid + 256];
        if (tid < YPAD) {
            yB[tid]               = INFV;
            yB[YPAD + NLEN + tid] = INFV;
        }
    }
    for (int k = tid; k < (FNW + 1) * FRROW; k += 256) ring[k] = INFV;
    __syncthreads();

    f32x2 xx0, xx1, xx2, xx3, xx4, xx5, xx6, xx7;
    {
        const float4 xa = *(const float4*)&X[tid * 8];
        const float4 xb = *(const float4*)&X[tid * 8 + 4];
        xx0 = (f32x2){xa.x, xa.x}; xx1 = (f32x2){xa.y, xa.y};
        xx2 = (f32x2){xa.z, xa.z}; xx3 = (f32x2){xa.w, xa.w};
        xx4 = (f32x2){xb.x, xb.x}; xx5 = (f32x2){xb.y, xb.y};
        xx6 = (f32x2){xb.z, xb.z}; xx7 = (f32x2){xb.w, xb.w};
    }

    float pB0 = INFV, pB1 = INFV, pB2 = INFV, pB3 = INFV;
    float pB4 = INFV, pB5 = INFV, pB6 = INFV, pB7 = INFV;
    float a7p = INFV;
    float uBp = (tid == 0) ? 0.0f : INFV;

    const float* ringR = ring + w * FRROW + FPAD;
    float*       ringW = ring + (w + 1) * FRROW + FPAD;

    for (int gb = 0; gb < FGTOT; gb += FCS) {
        const int tau0 = gb - w * FDSKEW;

        if (tau0 >= 0 && tau0 <= FTMAX) {
            const float rblk = ringR[tau0 + lane];
            f32x2 y2[FSPB];
            {
                const f32x2* yp = (const f32x2*)(yS + (tau0 - 2 * lane));
                #pragma unroll
                for (int k = 0; k < FSPB; ++k) y2[k] = yp[k];
            }
            float* wp = ringW + (tau0 - 2 * lane);
            const bool isout = (tau0 == FTMAX) & (w == FNW - 1) & (lane == 63);

            #pragma unroll
            for (int s = 0; s < FSPB; ++s) {
                const float riA = rdlane(rblk, 2 * s);
                const float riB = rdlane(rblk, 2 * s + 1);
                const float uA  = dpp_shr1(a7p, riA);
                const float uB  = dpp_shr1(pB7, riB);
                const f32x2 yv = y2[s];
                f32x2 d0 = xx0 - yv;
                float n0A = fmaf(d0.x, d0.x, min3f(pB0, uA,  uBp));
                float n0B = fmaf(d0.y, d0.y, min3f(n0A, uB,  uA));
                f32x2 d1 = xx1 - yv;
                float n1A = fmaf(d1.x, d1.x, min3f(pB1, n0A, pB0));
                float n1B = fmaf(d1.y, d1.y, min3f(n1A, n0B, n0A));
                f32x2 d2 = xx2 - yv;
                float n2A = fmaf(d2.x, d2.x, min3f(pB2, n1A, pB1));
                float n2B = fmaf(d2.y, d2.y, min3f(n2A, n1B, n1A));
                f32x2 d3 = xx3 - yv;
                float n3A = fmaf(d3.x, d3.x, min3f(pB3, n2A, pB2));
                float n3B = fmaf(d3.y, d3.y, min3f(n3A, n2B, n2A));
                f32x2 d4 = xx4 - yv;
                float n4A = fmaf(d4.x, d4.x, min3f(pB4, n3A, pB3));
                float n4B = fmaf(d4.y, d4.y, min3f(n4A, n3B, n3A));
                f32x2 d5 = xx5 - yv;
                float n5A = fmaf(d5.x, d5.x, min3f(pB5, n4A, pB4));
                float n5B = fmaf(d5.y, d5.y, min3f(n5A, n4B, n4A));
                f32x2 d6 = xx6 - yv;
                float n6A = fmaf(d6.x, d6.x, min3f(pB6, n5A, pB5));
                float n6B = fmaf(d6.y, d6.y, min3f(n6A, n5B, n5A));
                f32x2 d7 = xx7 - yv;
                float n7A = fmaf(d7.x, d7.x, min3f(pB7, n6A, pB6));
                float n7B = fmaf(d7.y, d7.y, min3f(n7A, n6B, n6A));
                f32x2 wv; wv.x = n7A; wv.y = n7B;
                *(f32x2*)(wp + 2 * s) = wv;
                uBp = uB; a7p = n7A;
                pB0 = n0B; pB1 = n1B; pB2 = n2B; pB3 = n3B;
                pB4 = n4B; pB5 = n5B; pB6 = n6B; pB7 = n7B;
                if (s == 30 && isout) out[0] = sqrtf(n7B);
            }
        }
        __syncthreads();
    }
}

extern "C" void kernel_launch(void* const* d_in, const int* in_sizes, int n_in,
                              void* d_out, int out_size, void* d_ws, size_t ws_size,
                              hipStream_t stream) {
    const float* x = (const float*)d_in[0];
    const float* y = (const float*)d_in[1];
    (void)in_sizes; (void)n_in; (void)out_size;
    if (d_ws != nullptr && ws_size >= 16384) {
        hipMemsetAsync(d_ws, 0, 1024, stream);       // zero the 3 flags
        dtw_kernel<<<4, 256, 0, stream>>>(x, y, (float*)d_out, (float*)d_ws);
    } else {
        dtw_kernel_fb<<<1, 256, 0, stream>>>(x, y, (float*)d_out);
    }
}

// Round 12
// 184.922 us; speedup vs baseline: 1.3344x; 1.3344x over previous
//
#include <hip/hip_runtime.h>
#include <math.h>

// DTW 2048x2048, squared-diff cost, out = sqrt(DTW[2047][2047]).
//
// TWO-CU pipeline (R10 structure, EXTRA 64->192): 2 blocks x 4 waves
// (1 wave/SIMD on two CUs), 8 strips of 256 rows; strip g = 4*blockIdx+w;
// lane l owns strip rows 4l..4l+3. Engine = R7's proven C=2 core
// (cols jA = tau0+2s-2l, jB = jA+1), CSTEP=64.
//
// WHY EXTRA=192 (round-12 change): R7 hits the pure issue cadence
// (235cy/step = 44 ops x 5.3); R10 pays 170cy/step for 25 ops = +37cy
// above cadence. R10's flag slack was TWO columns (required 254 = 126
// lane-lag + 64 copy-gran + 64 deferred-flag; provided DSKEW+EXTRA=256):
// the consumer's spin target is only satisfied by a flag published in
// the SAME gb-iteration on the other XCD -> every block eats cross-XCD
// flag-visibility latency, and the stall propagates down the wave chain.
// EXTRA=192 -> slack 130 cols (2 blocks, ~9us tolerance) at +128 cols
// ramp (GTOT 3584->3712). Model: 1856 steps x 133cy = ~103us (from 127).
// Null read (dur ~127): overhead is per-block fixed cost, not flag ->
// next lever is CSTEP=128. R9/R11 (CSTEP=32 deep pipelines) both lost.
//
// Flag protocol (agent scope, cross-XCD safe -- R8/R10-validated):
//   producer (b0,w3) end of block tau0:
//     if tau0>=128: __threadfence(); lane0 release-store flag = tau0-127
//       (covers copies issued at end of block tau0-64; vmcnt long
//        drained -> the fence is cheap)
//     copy grow[tau0-126+lane] = ringW[tau0-126+lane]  (256B coalesced)
//     if tau0==TAUMAX: __threadfence(); lane0 flag = FLAGBIG (tail:
//       copies cover cols <= 2049 >= 2047)
//   consumer (b1,w0) block tau0: needs cols <= min(tau0+63,2047) final;
//     prefetches next block's 64 ring values one block early (spin
//     target min(nt+63,2047)), so HBM latency hides under 32 steps.
//   Junk safety: cols >= 2048 junk-only flows rightward (never into
//     output col 2047); NaN/negative junk sorts LARGE under
//     unsigned-bitcast min3. No deadlock: b0 never waits; b1's targets
//     all eventually published (FLAGBIG). Flag memset per launch.
//
// Skews: strip g at g*192, +EXTRA for b1 -> b1w0 vs b0w3 gap = 384.
// Intra-block LDS ring proof unchanged (DSKEW=192: producer completed
// tau0+128, lane63 wrote <= tau0+65 >= tau0+63).
//
// Per step (25 VALU): 2 rdlane + 2 dpp_shr1 (u conveyor) + 4 v_pk_add_f32
// + 8 min3 (unsigned-bitcast -> v_min3_u32) + 8 fma + 1 ds_write_b64.
// Guard-free INFV=1e30 scheme as R7 (pads absorb OOB; junk sorts large).
//
// Output: b1/w3 (strip 7), lane 63, row 3 = global 2047, col jB = 2047
// at tau0 = 2112 (TAUMAX), s = 30.

#define NLEN   2048
#define NWL    4
#define CSTEP  64
#define SPB    (CSTEP / 2)
#define DSKEW  192
#define EXTRA  192
#define PAD    128
#define RROW   (PAD + 2176)            // ring cols -128..2175 -> 2304 floats
#define YPAD   128
#define TAUMAX 2112
#define GTOT   (TAUMAX + 7 * DSKEW + EXTRA + CSTEP)   // 3712
#define FLAGBIG (1 << 20)
#define INFV   1e30f

typedef float f32x2 __attribute__((ext_vector_type(2)));

__device__ __forceinline__ float dpp_shr1(float v, float inj) {
    int r = __builtin_amdgcn_update_dpp(
        __builtin_bit_cast(int, inj), __builtin_bit_cast(int, v),
        0x138 /*wave_shr:1*/, 0xF, 0xF, false /*lane0 keeps old=inj*/);
    return __builtin_bit_cast(float, r);
}
__device__ __forceinline__ float rdlane(float v, int l) {
    return __builtin_bit_cast(float,
        __builtin_amdgcn_readlane(__builtin_bit_cast(int, v), l));
}
// 3-input min on non-negative floats via unsigned bit-pattern compare;
// umin+umin fuses to a single v_min3_u32. NaN/inf/negative sort LARGE.
__device__ __forceinline__ float min3f(float a, float b, float c) {
    unsigned ia = __builtin_bit_cast(unsigned, a);
    unsigned ib = __builtin_bit_cast(unsigned, b);
    unsigned ic = __builtin_bit_cast(unsigned, c);
    unsigned m  = __builtin_elementwise_min(
                      __builtin_elementwise_min(ia, ib), ic);
    return __builtin_bit_cast(float, m);
}
__device__ __forceinline__ void spinflag(int* flag, int target) {
    while (__hip_atomic_load(flag, __ATOMIC_ACQUIRE,
                             __HIP_MEMORY_SCOPE_AGENT) < target)
        __builtin_amdgcn_s_sleep(2);
}

// ---------------- 2-block (2-CU) kernel ----------------
__global__ __launch_bounds__(256, 1) void dtw_kernel(const float* __restrict__ X,
                                                     const float* __restrict__ Y,
                                                     float* __restrict__ out,
                                                     float* __restrict__ ws) {
    int*   flag = (int*)ws;
    float* grow = ws + 16 + PAD;       // global ring base (col 0)

    __shared__ __align__(16) float yB[YPAD + NLEN + YPAD];
    __shared__ float ring[(NWL + 1) * RROW];
    float* yS = yB + YPAD;

    const int tid  = threadIdx.x;
    const int w    = tid >> 6;
    const int lane = tid & 63;
    const int b    = blockIdx.x;
    const int skew = (4 * b + w) * DSKEW + (b ? EXTRA : 0);
    const bool isprod = (b == 0) & (w == 3);
    const bool iscons = (b == 1) & (w == 0);

    {   // Y into LDS middle, INFV pads on both sides
        const float4* Y4 = (const float4*)Y;
        float4* y4 = (float4*)(yB + YPAD);
        y4[tid]       = Y4[tid];
        y4[tid + 256] = Y4[tid + 256];
        if (tid < YPAD) {
            yB[tid]               = INFV;
            yB[YPAD + NLEN + tid] = INFV;
        }
    }
    for (int k = tid; k < (NWL + 1) * RROW; k += 256) ring[k] = INFV;
    __syncthreads();

    f32x2 xx0, xx1, xx2, xx3;
    {   // strip rows: 256*(4b+w) + 4*lane
        const float4 xa = *(const float4*)&X[b * 1024 + w * 256 + lane * 4];
        xx0 = (f32x2){xa.x, xa.x}; xx1 = (f32x2){xa.y, xa.y};
        xx2 = (f32x2){xa.z, xa.z}; xx3 = (f32x2){xa.w, xa.w};
    }

    float pB0 = INFV, pB1 = INFV, pB2 = INFV, pB3 = INFV;
    float a3p = INFV;
    float uBp = (b == 0 && tid == 0) ? 0.0f : INFV;  // DTW[-1][-1]=0 seed
    float gcur = INFV, gnext = INFV;                 // consumer prefetch regs

    const float* ringR = ring + w * RROW + PAD;
    float*       ringW = ring + (w + 1) * RROW + PAD;

    for (int gb = 0; gb < GTOT; gb += CSTEP) {
        const int tau0 = gb - skew;

        if (tau0 >= 0 && tau0 <= TAUMAX) {
            float rblk;
            if (iscons) {
                if (tau0 == 0) {                       // prologue: first block
                    spinflag(flag, 63);
                    gcur = grow[lane];
                }
                const int nt = tau0 + CSTEP;           // prefetch next block
                if (nt <= TAUMAX) {
                    int tgt = nt + 63;
                    if (tgt > NLEN - 1) tgt = NLEN - 1;
                    spinflag(flag, tgt);
                    gnext = grow[nt + lane];
                }
                rblk = gcur;
            } else {
                rblk = ringR[tau0 + lane];             // 1 coalesced ds_read
            }

            f32x2 y2[SPB];
            {
                const f32x2* yp = (const f32x2*)(yS + (tau0 - 2 * lane));
                #pragma unroll
                for (int k = 0; k < SPB; ++k) y2[k] = yp[k];
            }
            float* wp = ringW + (tau0 - 2 * lane);
            const bool isout = (b == 1) & (w == 3) & (lane == 63)
                             & (tau0 == TAUMAX);

            #pragma unroll
            for (int s = 0; s < SPB; ++s) {
                const float riA = rdlane(rblk, 2 * s);
                const float riB = rdlane(rblk, 2 * s + 1);
                const float uA  = dpp_shr1(a3p, riA);
                const float uB  = dpp_shr1(pB3, riB);
                const f32x2 yv = y2[s];
                f32x2 d0 = xx0 - yv;
                float n0A = fmaf(d0.x, d0.x, min3f(pB0, uA,  uBp));
                float n0B = fmaf(d0.y, d0.y, min3f(n0A, uB,  uA));
                f32x2 d1 = xx1 - yv;
                float n1A = fmaf(d1.x, d1.x, min3f(pB1, n0A, pB0));
                float n1B = fmaf(d1.y, d1.y, min3f(n1A, n0B, n0A));
                f32x2 d2 = xx2 - yv;
                float n2A = fmaf(d2.x, d2.x, min3f(pB2, n1A, pB1));
                float n2B = fmaf(d2.y, d2.y, min3f(n2A, n1B, n1A));
                f32x2 d3 = xx3 - yv;
                float n3A = fmaf(d3.x, d3.x, min3f(pB3, n2A, pB2));
                float n3B = fmaf(d3.y, d3.y, min3f(n3A, n2B, n2A));
                f32x2 wv; wv.x = n3A; wv.y = n3B;
                *(f32x2*)(wp + 2 * s) = wv;            // ds_write_b64
                uBp = uB; a3p = n3A;
                pB0 = n0B; pB1 = n1B; pB2 = n2B; pB3 = n3B;
                if (s == 30 && isout) out[0] = sqrtf(n3B);  // col 2047
            }

            if (isprod) {
                // deferred flag: covers copies issued at end of PREVIOUS
                // block (vmcnt long drained -> cheap fence)
                if (tau0 >= 128) {
                    __threadfence();
                    if (lane == 0)
                        __hip_atomic_store(flag, tau0 - 127, __ATOMIC_RELEASE,
                                           __HIP_MEMORY_SCOPE_AGENT);
                }
                // this block's newly-final cols: ONE coalesced 256B copy
                grow[tau0 - 126 + lane] = ringW[tau0 - 126 + lane];
                if (tau0 == TAUMAX) {                  // tail: publish all
                    __threadfence();
                    if (lane == 0)
                        __hip_atomic_store(flag, FLAGBIG, __ATOMIC_RELEASE,
                                           __HIP_MEMORY_SCOPE_AGENT);
                }
            }
            if (iscons) gcur = gnext;
        }
        __syncthreads();
    }
}

// ---------------- fallback: R7 single-block kernel (proven 134.5us) ----------------
#define FNW    4
#define FGTOT  (TAUMAX + (FNW - 1) * DSKEW + CSTEP)   // 2752

__global__ __launch_bounds__(256, 1) void dtw_kernel_fb(const float* __restrict__ X,
                                                        const float* __restrict__ Y,
                                                        float* __restrict__ out) {
    __shared__ __align__(16) float yB[YPAD + NLEN + YPAD];
    __shared__ float ring[(FNW + 1) * RROW];
    float* yS = yB + YPAD;

    const int tid  = threadIdx.x;
    const int w    = tid >> 6;
    const int lane = tid & 63;

    {
        const float4* Y4 = (const float4*)Y;
        float4* y4 = (float4*)(yB + YPAD);
        y4[tid]       = Y4[tid];
        y4[tid + 256] = Y4[tid + 256];
        if (tid < YPAD) {
            yB[tid]               = INFV;
            yB[YPAD + NLEN + tid] = INFV;
        }
    }
    for (int k = tid; k < (FNW + 1) * RROW; k += 256) ring[k] = INFV;
    __syncthreads();

    f32x2 xx0, xx1, xx2, xx3, xx4, xx5, xx6, xx7;
    {
        const float4 xa = *(const float4*)&X[tid * 8];
        const float4 xb = *(const float4*)&X[tid * 8 + 4];
        xx0 = (f32x2){xa.x, xa.x}; xx1 = (f32x2){xa.y, xa.y};
        xx2 = (f32x2){xa.z, xa.z}; xx3 = (f32x2){xa.w, xa.w};
        xx4 = (f32x2){xb.x, xb.x}; xx5 = (f32x2){xb.y, xb.y};
        xx6 = (f32x2){xb.z, xb.z}; xx7 = (f32x2){xb.w, xb.w};
    }

    float pB0 = INFV, pB1 = INFV, pB2 = INFV, pB3 = INFV;
    float pB4 = INFV, pB5 = INFV, pB6 = INFV, pB7 = INFV;
    float a7p = INFV;
    float uBp = (tid == 0) ? 0.0f : INFV;

    const float* ringR = ring + w * RROW + PAD;
    float*       ringW = ring + (w + 1) * RROW + PAD;

    for (int gb = 0; gb < FGTOT; gb += CSTEP) {
        const int tau0 = gb - w * DSKEW;

        if (tau0 >= 0 && tau0 <= TAUMAX) {
            const float rblk = ringR[tau0 + lane];
            f32x2 y2[SPB];
            {
                const f32x2* yp = (const f32x2*)(yS + (tau0 - 2 * lane));
                #pragma unroll
                for (int k = 0; k < SPB; ++k) y2[k] = yp[k];
            }
            float* wp = ringW + (tau0 - 2 * lane);
            const bool isout = (tau0 == TAUMAX) & (w == FNW - 1) & (lane == 63);

            #pragma unroll
            for (int s = 0; s < SPB; ++s) {
                const float riA = rdlane(rblk, 2 * s);
                const float riB = rdlane(rblk, 2 * s + 1);
                const float uA  = dpp_shr1(a7p, riA);
                const float uB  = dpp_shr1(pB7, riB);
                const f32x2 yv = y2[s];
                f32x2 d0 = xx0 - yv;
                float n0A = fmaf(d0.x, d0.x, min3f(pB0, uA,  uBp));
                float n0B = fmaf(d0.y, d0.y, min3f(n0A, uB,  uA));
                f32x2 d1 = xx1 - yv;
                float n1A = fmaf(d1.x, d1.x, min3f(pB1, n0A, pB0));
                float n1B = fmaf(d1.y, d1.y, min3f(n1A, n0B, n0A));
                f32x2 d2 = xx2 - yv;
                float n2A = fmaf(d2.x, d2.x, min3f(pB2, n1A, pB1));
                float n2B = fmaf(d2.y, d2.y, min3f(n2A, n1B, n1A));
                f32x2 d3 = xx3 - yv;
                float n3A = fmaf(d3.x, d3.x, min3f(pB3, n2A, pB2));
                float n3B = fmaf(d3.y, d3.y, min3f(n3A, n2B, n2A));
                f32x2 d4 = xx4 - yv;
                float n4A = fmaf(d4.x, d4.x, min3f(pB4, n3A, pB3));
                float n4B = fmaf(d4.y, d4.y, min3f(n4A, n3B, n3A));
                f32x2 d5 = xx5 - yv;
                float n5A = fmaf(d5.x, d5.x, min3f(pB5, n4A, pB4));
                float n5B = fmaf(d5.y, d5.y, min3f(n5A, n4B, n4A));
                f32x2 d6 = xx6 - yv;
                float n6A = fmaf(d6.x, d6.x, min3f(pB6, n5A, pB5));
                float n6B = fmaf(d6.y, d6.y, min3f(n6A, n5B, n5A));
                f32x2 d7 = xx7 - yv;
                float n7A = fmaf(d7.x, d7.x, min3f(pB7, n6A, pB6));
                float n7B = fmaf(d7.y, d7.y, min3f(n7A, n6B, n6A));
                f32x2 wv; wv.x = n7A; wv.y = n7B;
                *(f32x2*)(wp + 2 * s) = wv;
                uBp = uB; a7p = n7A;
                pB0 = n0B; pB1 = n1B; pB2 = n2B; pB3 = n3B;
                pB4 = n4B; pB5 = n5B; pB6 = n6B; pB7 = n7B;
                if (s == 30 && isout) out[0] = sqrtf(n7B);
            }
        }
        __syncthreads();
    }
}

extern "C" void kernel_launch(void* const* d_in, const int* in_sizes, int n_in,
                              void* d_out, int out_size, void* d_ws, size_t ws_size,
                              hipStream_t stream) {
    const float* x = (const float*)d_in[0];
    const float* y = (const float*)d_in[1];
    (void)in_sizes; (void)n_in; (void)out_size;
    if (d_ws != nullptr && ws_size >= 16384) {
        hipMemsetAsync(d_ws, 0, 4, stream);          // zero the flag
        dtw_kernel<<<2, 256, 0, stream>>>(x, y, (float*)d_out, (float*)d_ws);
    } else {
        dtw_kernel_fb<<<1, 256, 0, stream>>>(x, y, (float*)d_out);
    }
}

// Round 13
// 183.816 us; speedup vs baseline: 1.3424x; 1.0060x over previous
//
#include <hip/hip_runtime.h>
#include <math.h>

// DTW 2048x2048, squared-diff cost, out = sqrt(DTW[2047][2047]).
//
// TWO-CU pipeline (R12 structure + consumer flag-caching): 2 blocks x 4
// waves (1 wave/SIMD on two CUs), 8 strips of 256 rows; strip g =
// 4*blockIdx+w; lane l owns strip rows 4l..4l+3. Engine = R7's C=2 core
// (cols jA = tau0+2s-2l, jB = jA+1), CSTEP=64, DSKEW=192, EXTRA=192.
//
// WHY flag-caching (round-13 change): R7 single-CU hits pure issue
// cadence (235cy/step = 44 ops x 5.34, ZERO per-block overhead); R10/R12
// pay +37cy/step (~1180cy/block) = entirely cross-CU machinery. The
// dominant term: the consumer's spinflag is an ACQUIRE ATOMIC LOAD of a
// cross-XCD line (~700cy) executed serially before compute TWICE per
// block even when satisfied -- the load latency, not the waiting, is the
// cost (that's why R12's extra slack was null: 127.3 == 127.5).
// Fix: (1) cache the flag in a register -- it's monotone, and each read
// returns producer progress ~ target+130 (EXTRA=192 slack), so ~2/3 of
// block-checks skip the atomic load; (2) grow reads become RELAXED
// agent-scope atomic loads (R8-validated) so the skip path needs no
// acquire: happens-before for cols <= cached-flag was established at the
// earlier acquire, and agent-atomic loads are coherent; (3) prefetched
// gnext latency hides under the 32-step compute (waitcnt at next-block
// use). Model: ~230cy/block overhead left -> 140cy/step -> ~108us.
//
// Flag protocol (agent scope, cross-XCD safe -- R8/R10/R12-validated):
//   producer (b0,w3) end of block tau0:
//     if tau0>=128: __threadfence(); lane0 release-store flag = tau0-127
//       (covers copies issued at end of block tau0-64; vmcnt drained)
//     copy grow[tau0-126+lane] = ringW[tau0-126+lane]  (256B coalesced)
//     if tau0==TAUMAX: __threadfence(); lane0 flag = FLAGBIG
//   consumer (b1,w0) block tau0: needs cols <= min(tau0+63,2047) final;
//     prefetches next block's 64 ring values one block early; flag check
//     target min(nt+63,2047) against cached fc first.
//   Junk safety: cols >= 2048 junk only flows rightward (never into
//     output col 2047); NaN/negative junk sorts LARGE under
//     unsigned-bitcast min3. No deadlock: b0 never waits; all consumer
//     targets eventually published (FLAGBIG). Flag memset per launch.
//
// Skews: strip g at g*192, +EXTRA=192 for b1 -> b1w0 vs b0w3 gap = 384,
// steady-state flag headroom = 384-254 = 130 cols (~2 blocks/read).
// Intra-block LDS ring proof unchanged (DSKEW=192: producer completed
// tau0+128, lane63 wrote <= tau0+65 >= tau0+63). GTOT = 3712.
//
// Per step (25 VALU): 2 rdlane + 2 dpp_shr1 (u conveyor) + 4 v_pk_add_f32
// + 8 min3 (unsigned-bitcast -> v_min3_u32) + 8 fma + 1 ds_write_b64.
// Guard-free INFV=1e30 scheme as R7 (pads absorb OOB; junk sorts large).
//
// Output: b1/w3 (strip 7), lane 63, row 3 = global 2047, col jB = 2047
// at tau0 = 2112 (TAUMAX), s = 30.

#define NLEN   2048
#define NWL    4
#define CSTEP  64
#define SPB    (CSTEP / 2)
#define DSKEW  192
#define EXTRA  192
#define PAD    128
#define RROW   (PAD + 2176)            // ring cols -128..2175 -> 2304 floats
#define YPAD   128
#define TAUMAX 2112
#define GTOT   (TAUMAX + 7 * DSKEW + EXTRA + CSTEP)   // 3712
#define FLAGBIG (1 << 20)
#define INFV   1e30f

typedef float f32x2 __attribute__((ext_vector_type(2)));

__device__ __forceinline__ float dpp_shr1(float v, float inj) {
    int r = __builtin_amdgcn_update_dpp(
        __builtin_bit_cast(int, inj), __builtin_bit_cast(int, v),
        0x138 /*wave_shr:1*/, 0xF, 0xF, false /*lane0 keeps old=inj*/);
    return __builtin_bit_cast(float, r);
}
__device__ __forceinline__ float rdlane(float v, int l) {
    return __builtin_bit_cast(float,
        __builtin_amdgcn_readlane(__builtin_bit_cast(int, v), l));
}
// 3-input min on non-negative floats via unsigned bit-pattern compare;
// umin+umin fuses to a single v_min3_u32. NaN/inf/negative sort LARGE.
__device__ __forceinline__ float min3f(float a, float b, float c) {
    unsigned ia = __builtin_bit_cast(unsigned, a);
    unsigned ib = __builtin_bit_cast(unsigned, b);
    unsigned ic = __builtin_bit_cast(unsigned, c);
    unsigned m  = __builtin_elementwise_min(
                      __builtin_elementwise_min(ia, ib), ic);
    return __builtin_bit_cast(float, m);
}
// Acquire spin that RETURNS the last-read flag value (for caching).
__device__ __forceinline__ int spinflag(int* flag, int target) {
    int f;
    while ((f = __hip_atomic_load(flag, __ATOMIC_ACQUIRE,
                                  __HIP_MEMORY_SCOPE_AGENT)) < target)
        __builtin_amdgcn_s_sleep(2);
    return f;
}
// Relaxed agent-scope atomic load (coherent read, no acquire fence).
__device__ __forceinline__ float gload(const float* p) {
    unsigned u = __hip_atomic_load((const unsigned*)p, __ATOMIC_RELAXED,
                                   __HIP_MEMORY_SCOPE_AGENT);
    return __builtin_bit_cast(float, u);
}

// ---------------- 2-block (2-CU) kernel ----------------
__global__ __launch_bounds__(256, 1) void dtw_kernel(const float* __restrict__ X,
                                                     const float* __restrict__ Y,
                                                     float* __restrict__ out,
                                                     float* __restrict__ ws) {
    int*   flag = (int*)ws;
    float* grow = ws + 16 + PAD;       // global ring base (col 0)

    __shared__ __align__(16) float yB[YPAD + NLEN + YPAD];
    __shared__ float ring[(NWL + 1) * RROW];
    float* yS = yB + YPAD;

    const int tid  = threadIdx.x;
    const int w    = tid >> 6;
    const int lane = tid & 63;
    const int b    = blockIdx.x;
    const int skew = (4 * b + w) * DSKEW + (b ? EXTRA : 0);
    const bool isprod = (b == 0) & (w == 3);
    const bool iscons = (b == 1) & (w == 0);

    {   // Y into LDS middle, INFV pads on both sides
        const float4* Y4 = (const float4*)Y;
        float4* y4 = (float4*)(yB + YPAD);
        y4[tid]       = Y4[tid];
        y4[tid + 256] = Y4[tid + 256];
        if (tid < YPAD) {
            yB[tid]               = INFV;
            yB[YPAD + NLEN + tid] = INFV;
        }
    }
    for (int k = tid; k < (NWL + 1) * RROW; k += 256) ring[k] = INFV;
    __syncthreads();

    f32x2 xx0, xx1, xx2, xx3;
    {   // strip rows: 256*(4b+w) + 4*lane
        const float4 xa = *(const float4*)&X[b * 1024 + w * 256 + lane * 4];
        xx0 = (f32x2){xa.x, xa.x}; xx1 = (f32x2){xa.y, xa.y};
        xx2 = (f32x2){xa.z, xa.z}; xx3 = (f32x2){xa.w, xa.w};
    }

    float pB0 = INFV, pB1 = INFV, pB2 = INFV, pB3 = INFV;
    float a3p = INFV;
    float uBp = (b == 0 && tid == 0) ? 0.0f : INFV;  // DTW[-1][-1]=0 seed
    float gcur = INFV, gnext = INFV;                 // consumer prefetch regs
    int   fc   = 0;                                  // cached flag value

    const float* ringR = ring + w * RROW + PAD;
    float*       ringW = ring + (w + 1) * RROW + PAD;

    for (int gb = 0; gb < GTOT; gb += CSTEP) {
        const int tau0 = gb - skew;

        if (tau0 >= 0 && tau0 <= TAUMAX) {
            float rblk;
            if (iscons) {
                if (tau0 == 0) {                       // prologue: first block
                    fc = spinflag(flag, 63);
                    gcur = gload(grow + lane);
                }
                const int nt = tau0 + CSTEP;           // prefetch next block
                if (nt <= TAUMAX) {
                    int tgt = nt + 63;
                    if (tgt > NLEN - 1) tgt = NLEN - 1;
                    if (fc < tgt) fc = spinflag(flag, tgt);  // usually skipped
                    gnext = gload(grow + nt + lane);   // latency hidden
                }
                rblk = gcur;
            } else {
                rblk = ringR[tau0 + lane];             // 1 coalesced ds_read
            }

            f32x2 y2[SPB];
            {
                const f32x2* yp = (const f32x2*)(yS + (tau0 - 2 * lane));
                #pragma unroll
                for (int k = 0; k < SPB; ++k) y2[k] = yp[k];
            }
            float* wp = ringW + (tau0 - 2 * lane);
            const bool isout = (b == 1) & (w == 3) & (lane == 63)
                             & (tau0 == TAUMAX);

            #pragma unroll
            for (int s = 0; s < SPB; ++s) {
                const float riA = rdlane(rblk, 2 * s);
                const float riB = rdlane(rblk, 2 * s + 1);
                const float uA  = dpp_shr1(a3p, riA);
                const float uB  = dpp_shr1(pB3, riB);
                const f32x2 yv = y2[s];
                f32x2 d0 = xx0 - yv;
                float n0A = fmaf(d0.x, d0.x, min3f(pB0, uA,  uBp));
                float n0B = fmaf(d0.y, d0.y, min3f(n0A, uB,  uA));
                f32x2 d1 = xx1 - yv;
                float n1A = fmaf(d1.x, d1.x, min3f(pB1, n0A, pB0));
                float n1B = fmaf(d1.y, d1.y, min3f(n1A, n0B, n0A));
                f32x2 d2 = xx2 - yv;
                float n2A = fmaf(d2.x, d2.x, min3f(pB2, n1A, pB1));
                float n2B = fmaf(d2.y, d2.y, min3f(n2A, n1B, n1A));
                f32x2 d3 = xx3 - yv;
                float n3A = fmaf(d3.x, d3.x, min3f(pB3, n2A, pB2));
                float n3B = fmaf(d3.y, d3.y, min3f(n3A, n2B, n2A));
                f32x2 wv; wv.x = n3A; wv.y = n3B;
                *(f32x2*)(wp + 2 * s) = wv;            // ds_write_b64
                uBp = uB; a3p = n3A;
                pB0 = n0B; pB1 = n1B; pB2 = n2B; pB3 = n3B;
                if (s == 30 && isout) out[0] = sqrtf(n3B);  // col 2047
            }

            if (isprod) {
                // deferred flag: covers copies issued at end of PREVIOUS
                // block (vmcnt long drained -> cheap fence)
                if (tau0 >= 128) {
                    __threadfence();
                    if (lane == 0)
                        __hip_atomic_store(flag, tau0 - 127, __ATOMIC_RELEASE,
                                           __HIP_MEMORY_SCOPE_AGENT);
                }
                // this block's newly-final cols: ONE coalesced 256B copy
                grow[tau0 - 126 + lane] = ringW[tau0 - 126 + lane];
                if (tau0 == TAUMAX) {                  // tail: publish all
                    __threadfence();
                    if (lane == 0)
                        __hip_atomic_store(flag, FLAGBIG, __ATOMIC_RELEASE,
                                           __HIP_MEMORY_SCOPE_AGENT);
                }
            }
            if (iscons) gcur = gnext;
        }
        __syncthreads();
    }
}

// ---------------- fallback: R7 single-block kernel (proven 134.5us) ----------------
#define FNW    4
#define FGTOT  (TAUMAX + (FNW - 1) * DSKEW + CSTEP)   // 2752

__global__ __launch_bounds__(256, 1) void dtw_kernel_fb(const float* __restrict__ X,
                                                        const float* __restrict__ Y,
                                                        float* __restrict__ out) {
    __shared__ __align__(16) float yB[YPAD + NLEN + YPAD];
    __shared__ float ring[(FNW + 1) * RROW];
    float* yS = yB + YPAD;

    const int tid  = threadIdx.x;
    const int w    = tid >> 6;
    const int lane = tid & 63;

    {
        const float4* Y4 = (const float4*)Y;
        float4* y4 = (float4*)(yB + YPAD);
        y4[tid]       = Y4[tid];
        y4[tid + 256] = Y4[tid + 256];
        if (tid < YPAD) {
            yB[tid]               = INFV;
            yB[YPAD + NLEN + tid] = INFV;
        }
    }
    for (int k = tid; k < (FNW + 1) * RROW; k += 256) ring[k] = INFV;
    __syncthreads();

    f32x2 xx0, xx1, xx2, xx3, xx4, xx5, xx6, xx7;
    {
        const float4 xa = *(const float4*)&X[tid * 8];
        const float4 xb = *(const float4*)&X[tid * 8 + 4];
        xx0 = (f32x2){xa.x, xa.x}; xx1 = (f32x2){xa.y, xa.y};
        xx2 = (f32x2){xa.z, xa.z}; xx3 = (f32x2){xa.w, xa.w};
        xx4 = (f32x2){xb.x, xb.x}; xx5 = (f32x2){xb.y, xb.y};
        xx6 = (f32x2){xb.z, xb.z}; xx7 = (f32x2){xb.w, xb.w};
    }

    float pB0 = INFV, pB1 = INFV, pB2 = INFV, pB3 = INFV;
    float pB4 = INFV, pB5 = INFV, pB6 = INFV, pB7 = INFV;
    float a7p = INFV;
    float uBp = (tid == 0) ? 0.0f : INFV;

    const float* ringR = ring + w * RROW + PAD;
    float*       ringW = ring + (w + 1) * RROW + PAD;

    for (int gb = 0; gb < FGTOT; gb += CSTEP) {
        const int tau0 = gb - w * DSKEW;

        if (tau0 >= 0 && tau0 <= TAUMAX) {
            const float rblk = ringR[tau0 + lane];
            f32x2 y2[SPB];
            {
                const f32x2* yp = (const f32x2*)(yS + (tau0 - 2 * lane));
                #pragma unroll
                for (int k = 0; k < SPB; ++k) y2[k] = yp[k];
            }
            float* wp = ringW + (tau0 - 2 * lane);
            const bool isout = (tau0 == TAUMAX) & (w == FNW - 1) & (lane == 63);

            #pragma unroll
            for (int s = 0; s < SPB; ++s) {
                const float riA = rdlane(rblk, 2 * s);
                const float riB = rdlane(rblk, 2 * s + 1);
                const float uA  = dpp_shr1(a7p, riA);
                const float uB  = dpp_shr1(pB7, riB);
                const f32x2 yv = y2[s];
                f32x2 d0 = xx0 - yv;
                float n0A = fmaf(d0.x, d0.x, min3f(pB0, uA,  uBp));
                float n0B = fmaf(d0.y, d0.y, min3f(n0A, uB,  uA));
                f32x2 d1 = xx1 - yv;
                float n1A = fmaf(d1.x, d1.x, min3f(pB1, n0A, pB0));
                float n1B = fmaf(d1.y, d1.y, min3f(n1A, n0B, n0A));
                f32x2 d2 = xx2 - yv;
                float n2A = fmaf(d2.x, d2.x, min3f(pB2, n1A, pB1));
                float n2B = fmaf(d2.y, d2.y, min3f(n2A, n1B, n1A));
                f32x2 d3 = xx3 - yv;
                float n3A = fmaf(d3.x, d3.x, min3f(pB3, n2A, pB2));
                float n3B = fmaf(d3.y, d3.y, min3f(n3A, n2B, n2A));
                f32x2 d4 = xx4 - yv;
                float n4A = fmaf(d4.x, d4.x, min3f(pB4, n3A, pB3));
                float n4B = fmaf(d4.y, d4.y, min3f(n4A, n3B, n3A));
                f32x2 d5 = xx5 - yv;
                float n5A = fmaf(d5.x, d5.x, min3f(pB5, n4A, pB4));
                float n5B = fmaf(d5.y, d5.y, min3f(n5A, n4B, n4A));
                f32x2 d6 = xx6 - yv;
                float n6A = fmaf(d6.x, d6.x, min3f(pB6, n5A, pB5));
                float n6B = fmaf(d6.y, d6.y, min3f(n6A, n5B, n5A));
                f32x2 d7 = xx7 - yv;
                float n7A = fmaf(d7.x, d7.x, min3f(pB7, n6A, pB6));
                float n7B = fmaf(d7.y, d7.y, min3f(n7A, n6B, n6A));
                f32x2 wv; wv.x = n7A; wv.y = n7B;
                *(f32x2*)(wp + 2 * s) = wv;
                uBp = uB; a7p = n7A;
                pB0 = n0B; pB1 = n1B; pB2 = n2B; pB3 = n3B;
                pB4 = n4B; pB5 = n5B; pB6 = n6B; pB7 = n7B;
                if (s == 30 && isout) out[0] = sqrtf(n7B);
            }
        }
        __syncthreads();
    }
}

extern "C" void kernel_launch(void* const* d_in, const int* in_sizes, int n_in,
                              void* d_out, int out_size, void* d_ws, size_t ws_size,
                              hipStream_t stream) {
    const float* x = (const float*)d_in[0];
    const float* y = (const float*)d_in[1];
    (void)in_sizes; (void)n_in; (void)out_size;
    if (d_ws != nullptr && ws_size >= 16384) {
        hipMemsetAsync(d_ws, 0, 4, stream);          // zero the flag
        dtw_kernel<<<2, 256, 0, stream>>>(x, y, (float*)d_out, (float*)d_ws);
    } else {
        dtw_kernel_fb<<<1, 256, 0, stream>>>(x, y, (float*)d_out);
    }
}

// Round 14
// 179.097 us; speedup vs baseline: 1.3778x; 1.0263x over previous
//
#include <hip/hip_runtime.h>
#include <math.h>

// DTW 2048x2048, squared-diff cost, out = sqrt(DTW[2047][2047]).
//
// TWO-CU pipeline (R13 structure, FENCELESS handoff): 2 blocks x 4 waves
// (1 wave/SIMD on two CUs), 8 strips of 256 rows; strip g = 4*blockIdx+w;
// lane l owns strip rows 4l..4l+3. Engine = R7's C=2 core (cols jA =
// tau0+2s-2l, jB = jA+1), CSTEP=64, DSKEW=192, EXTRA=192.
//
// WHY FENCELESS (round-14 change): R10/R12/R13 all land at 127us =
// +37cy/step over pure cadence; slack (R12) and consumer-acquire (R13)
// fixes were null. Remaining per-round cost: the producer's
// __threadfence() -- on gfx950 an agent-scope release compiles to
// s_waitcnt + buffer_wbl2 (L2 WRITEBACK, per-XCD non-coherent L2), paid
// every round by b0's barrier group, and b0 paces the pipeline
// (34 rounds x ~1000cy ~ 14us ~ the entire gap).
// Fix: no fence at all. (1) grow data stored as RELAXED AGENT-SCOPE
// ATOMIC stores -> write-through to the coherent point, bypassing L2
// (R8-validated data path; only 256B/round). (2) flag publish is already
// ONE ROUND DEFERRED, and __syncthreads() drains vmcnt(0) before
// s_barrier (m97 asm) -> by publish time the data is at the coherent
// point -> flag store can be RELAXED, no wbl2. (3) consumer: relaxed
// spin (no buffer_inv) + sched_barrier(0) to pin compiler ordering;
// data loads stay relaxed agent atomics (coherent point, no stale L2).
// Tail FLAGBIG moves one round later (tau0 == TAUMAX+64, barrier-drained).
// Model: per-step 170 -> ~135cy -> ~105-115us. Null -> 127 is the floor.
//
// Flag protocol (all relaxed agent atomics, ordering via barriers):
//   producer (b0,w3) round tau0:
//     [pre-engine] if tau0>=128: lane0 stores flag = tau0-127 (covers
//       cols <= tau0-127, stored at round tau0-64, drained by barrier)
//     [post-engine] 64 relaxed-atomic stores grow[tau0-126+lane]
//     [next rounds] at tau0 == TAUMAX+64: lane0 stores flag = FLAGBIG
//       (covers cols <= 2049 stored at round TAUMAX, drained by barrier)
//   consumer (b1,w0) round tau0: needs cols <= min(tau0+63,2047) final;
//     cached-flag skip (R13), relaxed spin + sched_barrier, relaxed
//     gloads prefetched one round early (latency hidden under 32 steps).
//   Junk safety: cols >= 2048 junk only flows rightward (never into
//     output col 2047); NaN/negative junk sorts LARGE under
//     unsigned-bitcast min3. No deadlock: b0 never waits; all consumer
//     targets eventually published (FLAGBIG). Flag memset per launch.
//
// Skews: strip g at g*192, +EXTRA=192 for b1 -> b1w0 vs b0w3 gap = 384,
// steady-state flag headroom 130 cols. Intra-block LDS ring proof
// unchanged (producer completed tau0+128, lane63 wrote <= tau0+65).
// GTOT = 3712.
//
// Per step (~26 VALU): 2 rdlane + 2 dpp_shr1 + 4 v_pk_add_f32 + 8 min3
// (unsigned-bitcast -> v_min3_u32) + 8 fma + 1 ds_write_b64 + 1 y2 read.
// Guard-free INFV=1e30 scheme as R7 (pads absorb OOB; junk sorts large).
//
// Output: b1/w3 (strip 7), lane 63, row 3 = global 2047, col jB = 2047
// at tau0 = 2112 (TAUMAX), s = 30.

#define NLEN   2048
#define NWL    4
#define CSTEP  64
#define SPB    (CSTEP / 2)
#define DSKEW  192
#define EXTRA  192
#define PAD    128
#define RROW   (PAD + 2176)            // ring cols -128..2175 -> 2304 floats
#define YPAD   128
#define TAUMAX 2112
#define GTOT   (TAUMAX + 7 * DSKEW + EXTRA + CSTEP)   // 3712
#define FLAGBIG (1 << 20)
#define INFV   1e30f

typedef float f32x2 __attribute__((ext_vector_type(2)));

__device__ __forceinline__ float dpp_shr1(float v, float inj) {
    int r = __builtin_amdgcn_update_dpp(
        __builtin_bit_cast(int, inj), __builtin_bit_cast(int, v),
        0x138 /*wave_shr:1*/, 0xF, 0xF, false /*lane0 keeps old=inj*/);
    return __builtin_bit_cast(float, r);
}
__device__ __forceinline__ float rdlane(float v, int l) {
    return __builtin_bit_cast(float,
        __builtin_amdgcn_readlane(__builtin_bit_cast(int, v), l));
}
// 3-input min on non-negative floats via unsigned bit-pattern compare;
// umin+umin fuses to a single v_min3_u32. NaN/inf/negative sort LARGE.
__device__ __forceinline__ float min3f(float a, float b, float c) {
    unsigned ia = __builtin_bit_cast(unsigned, a);
    unsigned ib = __builtin_bit_cast(unsigned, b);
    unsigned ic = __builtin_bit_cast(unsigned, c);
    unsigned m  = __builtin_elementwise_min(
                      __builtin_elementwise_min(ia, ib), ic);
    return __builtin_bit_cast(float, m);
}
// RELAXED spin (no buffer_inv); sched_barrier pins compiler ordering so
// data loads can't be hoisted above the observed flag value.
__device__ __forceinline__ int spinflag(int* flag, int target) {
    int f;
    while ((f = __hip_atomic_load(flag, __ATOMIC_RELAXED,
                                  __HIP_MEMORY_SCOPE_AGENT)) < target)
        __builtin_amdgcn_s_sleep(2);
    __builtin_amdgcn_sched_barrier(0);
    return f;
}
// Relaxed agent-scope atomic load/store: coherent point, bypass L2.
__device__ __forceinline__ float gload(const float* p) {
    unsigned u = __hip_atomic_load((const unsigned*)p, __ATOMIC_RELAXED,
                                   __HIP_MEMORY_SCOPE_AGENT);
    return __builtin_bit_cast(float, u);
}
__device__ __forceinline__ void gstore(float* p, float v) {
    __hip_atomic_store((unsigned*)p, __builtin_bit_cast(unsigned, v),
                       __ATOMIC_RELAXED, __HIP_MEMORY_SCOPE_AGENT);
}
__device__ __forceinline__ void fstore(int* p, int v) {
    __hip_atomic_store(p, v, __ATOMIC_RELAXED, __HIP_MEMORY_SCOPE_AGENT);
}

// ---------------- 2-block (2-CU) kernel ----------------
__global__ __launch_bounds__(256, 1) void dtw_kernel(const float* __restrict__ X,
                                                     const float* __restrict__ Y,
                                                     float* __restrict__ out,
                                                     float* __restrict__ ws) {
    int*   flag = (int*)ws;
    float* grow = ws + 16 + PAD;       // global ring base (col 0)

    __shared__ __align__(16) float yB[YPAD + NLEN + YPAD];
    __shared__ float ring[(NWL + 1) * RROW];
    float* yS = yB + YPAD;

    const int tid  = threadIdx.x;
    const int w    = tid >> 6;
    const int lane = tid & 63;
    const int b    = blockIdx.x;
    const int skew = (4 * b + w) * DSKEW + (b ? EXTRA : 0);
    const bool isprod = (b == 0) & (w == 3);
    const bool iscons = (b == 1) & (w == 0);

    {   // Y into LDS middle, INFV pads on both sides
        const float4* Y4 = (const float4*)Y;
        float4* y4 = (float4*)(yB + YPAD);
        y4[tid]       = Y4[tid];
        y4[tid + 256] = Y4[tid + 256];
        if (tid < YPAD) {
            yB[tid]               = INFV;
            yB[YPAD + NLEN + tid] = INFV;
        }
    }
    for (int k = tid; k < (NWL + 1) * RROW; k += 256) ring[k] = INFV;
    __syncthreads();

    f32x2 xx0, xx1, xx2, xx3;
    {   // strip rows: 256*(4b+w) + 4*lane
        const float4 xa = *(const float4*)&X[b * 1024 + w * 256 + lane * 4];
        xx0 = (f32x2){xa.x, xa.x}; xx1 = (f32x2){xa.y, xa.y};
        xx2 = (f32x2){xa.z, xa.z}; xx3 = (f32x2){xa.w, xa.w};
    }

    float pB0 = INFV, pB1 = INFV, pB2 = INFV, pB3 = INFV;
    float a3p = INFV;
    float uBp = (b == 0 && tid == 0) ? 0.0f : INFV;  // DTW[-1][-1]=0 seed
    float gcur = INFV, gnext = INFV;                 // consumer prefetch regs
    int   fc   = 0;                                  // cached flag value

    const float* ringR = ring + w * RROW + PAD;
    float*       ringW = ring + (w + 1) * RROW + PAD;

    for (int gb = 0; gb < GTOT; gb += CSTEP) {
        const int tau0 = gb - skew;

        // producer tail publish: round TAUMAX's stores are barrier-drained
        if (isprod && tau0 == TAUMAX + CSTEP && lane == 0)
            fstore(flag, FLAGBIG);

        if (tau0 >= 0 && tau0 <= TAUMAX) {
            // producer: deferred flag, covers stores of round tau0-64
            // (drained by the intervening __syncthreads vmcnt(0))
            if (isprod && tau0 >= 128 && lane == 0)
                fstore(flag, tau0 - 127);

            float rblk;
            if (iscons) {
                if (tau0 == 0) {                       // prologue: first block
                    fc = spinflag(flag, 63);
                    gcur = gload(grow + lane);
                }
                const int nt = tau0 + CSTEP;           // prefetch next block
                if (nt <= TAUMAX) {
                    int tgt = nt + 63;
                    if (tgt > NLEN - 1) tgt = NLEN - 1;
                    if (fc < tgt) fc = spinflag(flag, tgt);  // usually skipped
                    gnext = gload(grow + nt + lane);   // latency hidden
                }
                rblk = gcur;
            } else {
                rblk = ringR[tau0 + lane];             // 1 coalesced ds_read
            }

            f32x2 y2[SPB];
            {
                const f32x2* yp = (const f32x2*)(yS + (tau0 - 2 * lane));
                #pragma unroll
                for (int k = 0; k < SPB; ++k) y2[k] = yp[k];
            }
            float* wp = ringW + (tau0 - 2 * lane);
            const bool isout = (b == 1) & (w == 3) & (lane == 63)
                             & (tau0 == TAUMAX);

            #pragma unroll
            for (int s = 0; s < SPB; ++s) {
                const float riA = rdlane(rblk, 2 * s);
                const float riB = rdlane(rblk, 2 * s + 1);
                const float uA  = dpp_shr1(a3p, riA);
                const float uB  = dpp_shr1(pB3, riB);
                const f32x2 yv = y2[s];
                f32x2 d0 = xx0 - yv;
                float n0A = fmaf(d0.x, d0.x, min3f(pB0, uA,  uBp));
                float n0B = fmaf(d0.y, d0.y, min3f(n0A, uB,  uA));
                f32x2 d1 = xx1 - yv;
                float n1A = fmaf(d1.x, d1.x, min3f(pB1, n0A, pB0));
                float n1B = fmaf(d1.y, d1.y, min3f(n1A, n0B, n0A));
                f32x2 d2 = xx2 - yv;
                float n2A = fmaf(d2.x, d2.x, min3f(pB2, n1A, pB1));
                float n2B = fmaf(d2.y, d2.y, min3f(n2A, n1B, n1A));
                f32x2 d3 = xx3 - yv;
                float n3A = fmaf(d3.x, d3.x, min3f(pB3, n2A, pB2));
                float n3B = fmaf(d3.y, d3.y, min3f(n3A, n2B, n2A));
                f32x2 wv; wv.x = n3A; wv.y = n3B;
                *(f32x2*)(wp + 2 * s) = wv;            // ds_write_b64
                uBp = uB; a3p = n3A;
                pB0 = n0B; pB1 = n1B; pB2 = n2B; pB3 = n3B;
                if (s == 30 && isout) out[0] = sqrtf(n3B);  // col 2047
            }

            if (isprod) {
                // newly-final cols -> coherent point (write-through
                // relaxed agent atomics; 256B; drained at the barrier)
                gstore(grow + (tau0 - 126 + lane), ringW[tau0 - 126 + lane]);
            }
            if (iscons) gcur = gnext;
        }
        __syncthreads();
    }
}

// ---------------- fallback: R7 single-block kernel (proven 134.5us) ----------------
#define FNW    4
#define FGTOT  (TAUMAX + (FNW - 1) * DSKEW + CSTEP)   // 2752

__global__ __launch_bounds__(256, 1) void dtw_kernel_fb(const float* __restrict__ X,
                                                        const float* __restrict__ Y,
                                                        float* __restrict__ out) {
    __shared__ __align__(16) float yB[YPAD + NLEN + YPAD];
    __shared__ float ring[(FNW + 1) * RROW];
    float* yS = yB + YPAD;

    const int tid  = threadIdx.x;
    const int w    = tid >> 6;
    const int lane = tid & 63;

    {
        const float4* Y4 = (const float4*)Y;
        float4* y4 = (float4*)(yB + YPAD);
        y4[tid]       = Y4[tid];
        y4[tid + 256] = Y4[tid + 256];
        if (tid < YPAD) {
            yB[tid]               = INFV;
            yB[YPAD + NLEN + tid] = INFV;
        }
    }
    for (int k = tid; k < (FNW + 1) * RROW; k += 256) ring[k] = INFV;
    __syncthreads();

    f32x2 xx0, xx1, xx2, xx3, xx4, xx5, xx6, xx7;
    {
        const float4 xa = *(const float4*)&X[tid * 8];
        const float4 xb = *(const float4*)&X[tid * 8 + 4];
        xx0 = (f32x2){xa.x, xa.x}; xx1 = (f32x2){xa.y, xa.y};
        xx2 = (f32x2){xa.z, xa.z}; xx3 = (f32x2){xa.w, xa.w};
        xx4 = (f32x2){xb.x, xb.x}; xx5 = (f32x2){xb.y, xb.y};
        xx6 = (f32x2){xb.z, xb.z}; xx7 = (f32x2){xb.w, xb.w};
    }

    float pB0 = INFV, pB1 = INFV, pB2 = INFV, pB3 = INFV;
    float pB4 = INFV, pB5 = INFV, pB6 = INFV, pB7 = INFV;
    float a7p = INFV;
    float uBp = (tid == 0) ? 0.0f : INFV;

    const float* ringR = ring + w * RROW + PAD;
    float*       ringW = ring + (w + 1) * RROW + PAD;

    for (int gb = 0; gb < FGTOT; gb += CSTEP) {
        const int tau0 = gb - w * DSKEW;

        if (tau0 >= 0 && tau0 <= TAUMAX) {
            const float rblk = ringR[tau0 + lane];
            f32x2 y2[SPB];
            {
                const f32x2* yp = (const f32x2*)(yS + (tau0 - 2 * lane));
                #pragma unroll
                for (int k = 0; k < SPB; ++k) y2[k] = yp[k];
            }
            float* wp = ringW + (tau0 - 2 * lane);
            const bool isout = (tau0 == TAUMAX) & (w == FNW - 1) & (lane == 63);

            #pragma unroll
            for (int s = 0; s < SPB; ++s) {
                const float riA = rdlane(rblk, 2 * s);
                const float riB = rdlane(rblk, 2 * s + 1);
                const float uA  = dpp_shr1(a7p, riA);
                const float uB  = dpp_shr1(pB7, riB);
                const f32x2 yv = y2[s];
                f32x2 d0 = xx0 - yv;
                float n0A = fmaf(d0.x, d0.x, min3f(pB0, uA,  uBp));
                float n0B = fmaf(d0.y, d0.y, min3f(n0A, uB,  uA));
                f32x2 d1 = xx1 - yv;
                float n1A = fmaf(d1.x, d1.x, min3f(pB1, n0A, pB0));
                float n1B = fmaf(d1.y, d1.y, min3f(n1A, n0B, n0A));
                f32x2 d2 = xx2 - yv;
                float n2A = fmaf(d2.x, d2.x, min3f(pB2, n1A, pB1));
                float n2B = fmaf(d2.y, d2.y, min3f(n2A, n1B, n1A));
                f32x2 d3 = xx3 - yv;
                float n3A = fmaf(d3.x, d3.x, min3f(pB3, n2A, pB2));
                float n3B = fmaf(d3.y, d3.y, min3f(n3A, n2B, n2A));
                f32x2 d4 = xx4 - yv;
                float n4A = fmaf(d4.x, d4.x, min3f(pB4, n3A, pB3));
                float n4B = fmaf(d4.y, d4.y, min3f(n4A, n3B, n3A));
                f32x2 d5 = xx5 - yv;
                float n5A = fmaf(d5.x, d5.x, min3f(pB5, n4A, pB4));
                float n5B = fmaf(d5.y, d5.y, min3f(n5A, n4B, n4A));
                f32x2 d6 = xx6 - yv;
                float n6A = fmaf(d6.x, d6.x, min3f(pB6, n5A, pB5));
                float n6B = fmaf(d6.y, d6.y, min3f(n6A, n5B, n5A));
                f32x2 d7 = xx7 - yv;
                float n7A = fmaf(d7.x, d7.x, min3f(pB7, n6A, pB6));
                float n7B = fmaf(d7.y, d7.y, min3f(n7A, n6B, n6A));
                f32x2 wv; wv.x = n7A; wv.y = n7B;
                *(f32x2*)(wp + 2 * s) = wv;
                uBp = uB; a7p = n7A;
                pB0 = n0B; pB1 = n1B; pB2 = n2B; pB3 = n3B;
                pB4 = n4B; pB5 = n5B; pB6 = n6B; pB7 = n7B;
                if (s == 30 && isout) out[0] = sqrtf(n7B);
            }
        }
        __syncthreads();
    }
}

extern "C" void kernel_launch(void* const* d_in, const int* in_sizes, int n_in,
                              void* d_out, int out_size, void* d_ws, size_t ws_size,
                              hipStream_t stream) {
    const float* x = (const float*)d_in[0];
    const float* y = (const float*)d_in[1];
    (void)in_sizes; (void)n_in; (void)out_size;
    if (d_ws != nullptr && ws_size >= 16384) {
        hipMemsetAsync(d_ws, 0, 4, stream);          // zero the flag
        dtw_kernel<<<2, 256, 0, stream>>>(x, y, (float*)d_out, (float*)d_ws);
    } else {
        dtw_kernel_fb<<<1, 256, 0, stream>>>(x, y, (float*)d_out);
    }
}

// Round 15
// 175.996 us; speedup vs baseline: 1.4021x; 1.0176x over previous
//
#include <hip/hip_runtime.h>
#include <math.h>

// DTW 2048x2048, squared-diff cost, out = sqrt(DTW[2047][2047]).
//
// TWO-CU pipeline (R14 structure, EARLY-COPY handoff): 2 blocks x 4 waves
// (1 wave/SIMD on two CUs), 8 strips of 256 rows; strip g = 4*blockIdx+w;
// lane l owns strip rows 4l..4l+3. Engine = R7's C=2 core (cols jA =
// tau0+2s-2l, jB = jA+1), CSTEP=64, DSKEW=192, EXTRA=256.
//
// WHY EARLY COPY (round-15 change): R14 (fenceless) = 123.8us, still
// +27cy/step over pure cadence (133). Residual diagnosed: the producer
// issues its 64 write-through agent-atomic stores at the END of the
// round, right before __syncthreads -> the barrier's vmcnt(0) drain
// waits the full ~800cy store-retire latency; 800/32 steps = 25cy/step
// = the residual. Fix: issue the copy at the START of the round, for
// the cols finalized in the PREVIOUS round ([tau0-190, tau0-127], stable
// in the LDS ring) -> the ~5000cy engine hides the retire entirely.
// Flag deferral grows one round (covers <= tau0-191); EXTRA 192->256
// keeps the 2-round publish-visibility tolerance (at 2-round lag the
// flag covers tau_c+129 >= tau_c+127). Tail: copy [1986,2049] at
// tau0==TAUMAX+64, FLAGBIG at TAUMAX+128 (both barrier-drained;
// consumer's last need is 2 rounds later). GTOT 3712->3776 (+0.9%).
// Model: 160 -> ~137cy/step -> ~108us. Null -> ~123 is the floor.
//
// Protocol (all relaxed agent atomics, ordering via barrier drains):
//   producer (b0,w3) round tau0 PRE-ENGINE:
//     tau0 in [192, TAUMAX+64]: lane0 flag = tau0-191 (covers stores
//       issued at round tau0-64, drained by that round's barrier)
//     tau0 == TAUMAX+128: lane0 flag = FLAGBIG
//     tau0 in [128, TAUMAX+64]: 64 relaxed-atomic stores
//       grow[tau0-190+lane] = ringW[tau0-190+lane]  (prev round's cols;
//       disjoint from this round's engine writes [tau0-126, tau0+63])
//   consumer (b1,w0) round tau0: needs cols <= min(tau0+127,2047) for
//     the next-round prefetch; cached-flag skip (R13), relaxed spin +
//     sched_barrier, relaxed gloads one round early (latency hidden).
//   Junk safety: cols >= 2048 junk only flows rightward (never into
//     output col 2047); NaN/negative junk sorts LARGE under
//     unsigned-bitcast min3. No deadlock: b0 never waits; all consumer
//     targets eventually published (FLAGBIG). Flag memset per launch.
//
// Skews: strip g at g*192, +EXTRA=256 for b1 -> b1w0 vs b0w3 gap = 448.
// Prologue: consumer tau0=0 at gb=1024; producer by then published
// flag=257 (tau_p=448) and copied cols [0,63] (tau_p~254). Intra-block
// LDS ring proof unchanged. GTOT = 2112 + 7*192 + 256 + 64 = 3776.
//
// Per step (~26 VALU): 2 rdlane + 2 dpp_shr1 + 4 v_pk_add_f32 + 8 min3
// (unsigned-bitcast -> v_min3_u32) + 8 fma + 1 ds_write_b64 + 1 y2 read.
// Guard-free INFV=1e30 scheme as R7 (pads absorb OOB; junk sorts large).
//
// Output: b1/w3 (strip 7), lane 63, row 3 = global 2047, col jB = 2047
// at tau0 = 2112 (TAUMAX), s = 30.

#define NLEN   2048
#define NWL    4
#define CSTEP  64
#define SPB    (CSTEP / 2)
#define DSKEW  192
#define EXTRA  256
#define PAD    128
#define RROW   (PAD + 2176)            // ring cols -128..2175 -> 2304 floats
#define YPAD   128
#define TAUMAX 2112
#define GTOT   (TAUMAX + 7 * DSKEW + EXTRA + CSTEP)   // 3776
#define FLAGBIG (1 << 20)
#define INFV   1e30f

typedef float f32x2 __attribute__((ext_vector_type(2)));

__device__ __forceinline__ float dpp_shr1(float v, float inj) {
    int r = __builtin_amdgcn_update_dpp(
        __builtin_bit_cast(int, inj), __builtin_bit_cast(int, v),
        0x138 /*wave_shr:1*/, 0xF, 0xF, false /*lane0 keeps old=inj*/);
    return __builtin_bit_cast(float, r);
}
__device__ __forceinline__ float rdlane(float v, int l) {
    return __builtin_bit_cast(float,
        __builtin_amdgcn_readlane(__builtin_bit_cast(int, v), l));
}
// 3-input min on non-negative floats via unsigned bit-pattern compare;
// umin+umin fuses to a single v_min3_u32. NaN/inf/negative sort LARGE.
__device__ __forceinline__ float min3f(float a, float b, float c) {
    unsigned ia = __builtin_bit_cast(unsigned, a);
    unsigned ib = __builtin_bit_cast(unsigned, b);
    unsigned ic = __builtin_bit_cast(unsigned, c);
    unsigned m  = __builtin_elementwise_min(
                      __builtin_elementwise_min(ia, ib), ic);
    return __builtin_bit_cast(float, m);
}
// RELAXED spin (no buffer_inv); sched_barrier pins compiler ordering so
// data loads can't be hoisted above the observed flag value.
__device__ __forceinline__ int spinflag(int* flag, int target) {
    int f;
    while ((f = __hip_atomic_load(flag, __ATOMIC_RELAXED,
                                  __HIP_MEMORY_SCOPE_AGENT)) < target)
        __builtin_amdgcn_s_sleep(2);
    __builtin_amdgcn_sched_barrier(0);
    return f;
}
// Relaxed agent-scope atomic load/store: coherent point, bypass L2.
__device__ __forceinline__ float gload(const float* p) {
    unsigned u = __hip_atomic_load((const unsigned*)p, __ATOMIC_RELAXED,
                                   __HIP_MEMORY_SCOPE_AGENT);
    return __builtin_bit_cast(float, u);
}
__device__ __forceinline__ void gstore(float* p, float v) {
    __hip_atomic_store((unsigned*)p, __builtin_bit_cast(unsigned, v),
                       __ATOMIC_RELAXED, __HIP_MEMORY_SCOPE_AGENT);
}
__device__ __forceinline__ void fstore(int* p, int v) {
    __hip_atomic_store(p, v, __ATOMIC_RELAXED, __HIP_MEMORY_SCOPE_AGENT);
}

// ---------------- 2-block (2-CU) kernel ----------------
__global__ __launch_bounds__(256, 1) void dtw_kernel(const float* __restrict__ X,
                                                     const float* __restrict__ Y,
                                                     float* __restrict__ out,
                                                     float* __restrict__ ws) {
    int*   flag = (int*)ws;
    float* grow = ws + 16 + PAD;       // global ring base (col 0)

    __shared__ __align__(16) float yB[YPAD + NLEN + YPAD];
    __shared__ float ring[(NWL + 1) * RROW];
    float* yS = yB + YPAD;

    const int tid  = threadIdx.x;
    const int w    = tid >> 6;
    const int lane = tid & 63;
    const int b    = blockIdx.x;
    const int skew = (4 * b + w) * DSKEW + (b ? EXTRA : 0);
    const bool isprod = (b == 0) & (w == 3);
    const bool iscons = (b == 1) & (w == 0);

    {   // Y into LDS middle, INFV pads on both sides
        const float4* Y4 = (const float4*)Y;
        float4* y4 = (float4*)(yB + YPAD);
        y4[tid]       = Y4[tid];
        y4[tid + 256] = Y4[tid + 256];
        if (tid < YPAD) {
            yB[tid]               = INFV;
            yB[YPAD + NLEN + tid] = INFV;
        }
    }
    for (int k = tid; k < (NWL + 1) * RROW; k += 256) ring[k] = INFV;
    __syncthreads();

    f32x2 xx0, xx1, xx2, xx3;
    {   // strip rows: 256*(4b+w) + 4*lane
        const float4 xa = *(const float4*)&X[b * 1024 + w * 256 + lane * 4];
        xx0 = (f32x2){xa.x, xa.x}; xx1 = (f32x2){xa.y, xa.y};
        xx2 = (f32x2){xa.z, xa.z}; xx3 = (f32x2){xa.w, xa.w};
    }

    float pB0 = INFV, pB1 = INFV, pB2 = INFV, pB3 = INFV;
    float a3p = INFV;
    float uBp = (b == 0 && tid == 0) ? 0.0f : INFV;  // DTW[-1][-1]=0 seed
    float gcur = INFV, gnext = INFV;                 // consumer prefetch regs
    int   fc   = 0;                                  // cached flag value

    const float* ringR = ring + w * RROW + PAD;
    float*       ringW = ring + (w + 1) * RROW + PAD;

    for (int gb = 0; gb < GTOT; gb += CSTEP) {
        const int tau0 = gb - skew;

        // -------- producer pre-engine: flag publish + EARLY copy --------
        // (stores issued here retire under this round's ~5000cy engine,
        //  so the barrier's vmcnt(0) drain is free)
        if (isprod) {
            if (lane == 0 && tau0 >= 192 && tau0 <= TAUMAX + 2 * CSTEP)
                fstore(flag, tau0 - 191);            // covers round tau0-64
            if (lane == 0 && tau0 == TAUMAX + 2 * CSTEP)
                fstore(flag, FLAGBIG);               // tail (drained 2 rounds ago)
            if (tau0 >= 128 && tau0 <= TAUMAX + CSTEP) {
                const int c = tau0 - 190 + lane;     // prev round's final cols
                gstore(grow + c, ringW[c]);
            }
        }

        if (tau0 >= 0 && tau0 <= TAUMAX) {
            float rblk;
            if (iscons) {
                if (tau0 == 0) {                       // prologue: first block
                    fc = spinflag(flag, 63);
                    gcur = gload(grow + lane);
                }
                const int nt = tau0 + CSTEP;           // prefetch next block
                if (nt <= TAUMAX) {
                    int tgt = nt + 63;
                    if (tgt > NLEN - 1) tgt = NLEN - 1;
                    if (fc < tgt) fc = spinflag(flag, tgt);  // usually skipped
                    gnext = gload(grow + nt + lane);   // latency hidden
                }
                rblk = gcur;
            } else {
                rblk = ringR[tau0 + lane];             // 1 coalesced ds_read
            }

            f32x2 y2[SPB];
            {
                const f32x2* yp = (const f32x2*)(yS + (tau0 - 2 * lane));
                #pragma unroll
                for (int k = 0; k < SPB; ++k) y2[k] = yp[k];
            }
            float* wp = ringW + (tau0 - 2 * lane);
            const bool isout = (b == 1) & (w == 3) & (lane == 63)
                             & (tau0 == TAUMAX);

            #pragma unroll
            for (int s = 0; s < SPB; ++s) {
                const float riA = rdlane(rblk, 2 * s);
                const float riB = rdlane(rblk, 2 * s + 1);
                const float uA  = dpp_shr1(a3p, riA);
                const float uB  = dpp_shr1(pB3, riB);
                const f32x2 yv = y2[s];
                f32x2 d0 = xx0 - yv;
                float n0A = fmaf(d0.x, d0.x, min3f(pB0, uA,  uBp));
                float n0B = fmaf(d0.y, d0.y, min3f(n0A, uB,  uA));
                f32x2 d1 = xx1 - yv;
                float n1A = fmaf(d1.x, d1.x, min3f(pB1, n0A, pB0));
                float n1B = fmaf(d1.y, d1.y, min3f(n1A, n0B, n0A));
                f32x2 d2 = xx2 - yv;
                float n2A = fmaf(d2.x, d2.x, min3f(pB2, n1A, pB1));
                float n2B = fmaf(d2.y, d2.y, min3f(n2A, n1B, n1A));
                f32x2 d3 = xx3 - yv;
                float n3A = fmaf(d3.x, d3.x, min3f(pB3, n2A, pB2));
                float n3B = fmaf(d3.y, d3.y, min3f(n3A, n2B, n2A));
                f32x2 wv; wv.x = n3A; wv.y = n3B;
                *(f32x2*)(wp + 2 * s) = wv;            // ds_write_b64
                uBp = uB; a3p = n3A;
                pB0 = n0B; pB1 = n1B; pB2 = n2B; pB3 = n3B;
                if (s == 30 && isout) out[0] = sqrtf(n3B);  // col 2047
            }

            if (iscons) gcur = gnext;
        }
        __syncthreads();
    }
}

// ---------------- fallback: R7 single-block kernel (proven 134.5us) ----------------
#define FNW    4
#define FGTOT  (TAUMAX + (FNW - 1) * DSKEW + CSTEP)   // 2752

__global__ __launch_bounds__(256, 1) void dtw_kernel_fb(const float* __restrict__ X,
                                                        const float* __restrict__ Y,
                                                        float* __restrict__ out) {
    __shared__ __align__(16) float yB[YPAD + NLEN + YPAD];
    __shared__ float ring[(FNW + 1) * RROW];
    float* yS = yB + YPAD;

    const int tid  = threadIdx.x;
    const int w    = tid >> 6;
    const int lane = tid & 63;

    {
        const float4* Y4 = (const float4*)Y;
        float4* y4 = (float4*)(yB + YPAD);
        y4[tid]       = Y4[tid];
        y4[tid + 256] = Y4[tid + 256];
        if (tid < YPAD) {
            yB[tid]               = INFV;
            yB[YPAD + NLEN + tid] = INFV;
        }
    }
    for (int k = tid; k < (FNW + 1) * RROW; k += 256) ring[k] = INFV;
    __syncthreads();

    f32x2 xx0, xx1, xx2, xx3, xx4, xx5, xx6, xx7;
    {
        const float4 xa = *(const float4*)&X[tid * 8];
        const float4 xb = *(const float4*)&X[tid * 8 + 4];
        xx0 = (f32x2){xa.x, xa.x}; xx1 = (f32x2){xa.y, xa.y};
        xx2 = (f32x2){xa.z, xa.z}; xx3 = (f32x2){xa.w, xa.w};
        xx4 = (f32x2){xb.x, xb.x}; xx5 = (f32x2){xb.y, xb.y};
        xx6 = (f32x2){xb.z, xb.z}; xx7 = (f32x2){xb.w, xb.w};
    }

    float pB0 = INFV, pB1 = INFV, pB2 = INFV, pB3 = INFV;
    float pB4 = INFV, pB5 = INFV, pB6 = INFV, pB7 = INFV;
    float a7p = INFV;
    float uBp = (tid == 0) ? 0.0f : INFV;

    const float* ringR = ring + w * RROW + PAD;
    float*       ringW = ring + (w + 1) * RROW + PAD;

    for (int gb = 0; gb < FGTOT; gb += CSTEP) {
        const int tau0 = gb - w * DSKEW;

        if (tau0 >= 0 && tau0 <= TAUMAX) {
            const float rblk = ringR[tau0 + lane];
            f32x2 y2[SPB];
            {
                const f32x2* yp = (const f32x2*)(yS + (tau0 - 2 * lane));
                #pragma unroll
                for (int k = 0; k < SPB; ++k) y2[k] = yp[k];
            }
            float* wp = ringW + (tau0 - 2 * lane);
            const bool isout = (tau0 == TAUMAX) & (w == FNW - 1) & (lane == 63);

            #pragma unroll
            for (int s = 0; s < SPB; ++s) {
                const float riA = rdlane(rblk, 2 * s);
                const float riB = rdlane(rblk, 2 * s + 1);
                const float uA  = dpp_shr1(a7p, riA);
                const float uB  = dpp_shr1(pB7, riB);
                const f32x2 yv = y2[s];
                f32x2 d0 = xx0 - yv;
                float n0A = fmaf(d0.x, d0.x, min3f(pB0, uA,  uBp));
                float n0B = fmaf(d0.y, d0.y, min3f(n0A, uB,  uA));
                f32x2 d1 = xx1 - yv;
                float n1A = fmaf(d1.x, d1.x, min3f(pB1, n0A, pB0));
                float n1B = fmaf(d1.y, d1.y, min3f(n1A, n0B, n0A));
                f32x2 d2 = xx2 - yv;
                float n2A = fmaf(d2.x, d2.x, min3f(pB2, n1A, pB1));
                float n2B = fmaf(d2.y, d2.y, min3f(n2A, n1B, n1A));
                f32x2 d3 = xx3 - yv;
                float n3A = fmaf(d3.x, d3.x, min3f(pB3, n2A, pB2));
                float n3B = fmaf(d3.y, d3.y, min3f(n3A, n2B, n2A));
                f32x2 d4 = xx4 - yv;
                float n4A = fmaf(d4.x, d4.x, min3f(pB4, n3A, pB3));
                float n4B = fmaf(d4.y, d4.y, min3f(n4A, n3B, n3A));
                f32x2 d5 = xx5 - yv;
                float n5A = fmaf(d5.x, d5.x, min3f(pB5, n4A, pB4));
                float n5B = fmaf(d5.y, d5.y, min3f(n5A, n4B, n4A));
                f32x2 d6 = xx6 - yv;
                float n6A = fmaf(d6.x, d6.x, min3f(pB6, n5A, pB5));
                float n6B = fmaf(d6.y, d6.y, min3f(n6A, n5B, n5A));
                f32x2 d7 = xx7 - yv;
                float n7A = fmaf(d7.x, d7.x, min3f(pB7, n6A, pB6));
                float n7B = fmaf(d7.y, d7.y, min3f(n7A, n6B, n6A));
                f32x2 wv; wv.x = n7A; wv.y = n7B;
                *(f32x2*)(wp + 2 * s) = wv;
                uBp = uB; a7p = n7A;
                pB0 = n0B; pB1 = n1B; pB2 = n2B; pB3 = n3B;
                pB4 = n4B; pB5 = n5B; pB6 = n6B; pB7 = n7B;
                if (s == 30 && isout) out[0] = sqrtf(n7B);
            }
        }
        __syncthreads();
    }
}

extern "C" void kernel_launch(void* const* d_in, const int* in_sizes, int n_in,
                              void* d_out, int out_size, void* d_ws, size_t ws_size,
                              hipStream_t stream) {
    const float* x = (const float*)d_in[0];
    const float* y = (const float*)d_in[1];
    (void)in_sizes; (void)n_in; (void)out_size;
    if (d_ws != nullptr && ws_size >= 16384) {
        hipMemsetAsync(d_ws, 0, 4, stream);          // zero the flag
        dtw_kernel<<<2, 256, 0, stream>>>(x, y, (float*)d_out, (float*)d_ws);
    } else {
        dtw_kernel_fb<<<1, 256, 0, stream>>>(x, y, (float*)d_out);
    }
}

// Round 16
// 165.415 us; speedup vs baseline: 1.4918x; 1.0640x over previous
//
#include <hip/hip_runtime.h>
#include <math.h>

// DTW 2048x2048, squared-diff cost, out = sqrt(DTW[2047][2047]).
//
// TWO-CU pipeline (R14 structure + BROADCAST ring reads): 2 blocks x 4
// waves (1 wave/SIMD on two CUs), 8 strips of 256 rows; strip g =
// 4*blockIdx+w; lane l owns strip rows 4l..4l+3. Engine = R7's C=2 core
// (cols jA = tau0+2s-2l, jB = jA+1), CSTEP=64, DSKEW=192, EXTRA=192.
//
// WHY BROADCAST (round-16 change): R14 = 123.8us = 160cy/step at ~27
// VALU/step; VALUBusy 37%/CU -> the binding constraint is the measured
// ~5.34cy-per-VALU-op slope at 1 wave/SIMD (R7 and R14 both sit on it).
// The only lever that has consistently worked is ops/step. The per-step
// conveyor injection still costs 4 ops: 2 v_readlane + the 2 v_movs they
// force (rdlane -> SGPR; update_dpp's inj operand needs a VGPR).
// Replace with uniform-address LDS reads: once per round, rv[16] f32x4 =
// ring cols tau0..tau0+63 (16 ds_read_b128, wave-uniform = conflict-free
// broadcast, ~32cy issue amortized over 32 steps); per step riA/riB are
// compile-time register extracts = ZERO VALU. Consumer joins via cscr[64]
// LDS scratch: prefetched gnext parked at round-end, read uniformly next
// round (same-wave LDS ordering; R11's proven mechanism without R11's
// CSTEP=32/threadfence baggage). R15's early-copy reverted (null).
// Model: -4 ops x 5.34 = -21cy/step -> ~140cy/step -> ~108us.
//
// Protocol (R14 verbatim -- all relaxed agent atomics, barrier drains):
//   producer (b0,w3): pre-engine, tau0>=128: lane0 flag = tau0-127
//     (covers copies of round tau0-64, drained by that round's barrier);
//     post-engine: 64 relaxed-atomic stores grow[tau0-126+lane];
//     tau0==TAUMAX+64 (pre-check): flag = FLAGBIG (barrier-drained).
//   consumer (b1,w0): needs cols <= min(tau0+63,2047); cached-flag skip,
//     relaxed spin + sched_barrier, relaxed gloads one round early.
//   Junk safety: cols >= 2048 junk flows rightward only; NaN/negative
//   junk sorts LARGE under unsigned-bitcast min3. No deadlock. Flag
//   memset per launch.
//
// Skews: strip g at g*192, +EXTRA=192 for b1 (gap 384, headroom 130).
// Intra-block LDS ring proof unchanged (producer completed tau0+128,
// lane63 wrote <= tau0+65 >= tau0+63). GTOT = 3712.
//
// Per step (~23 VALU): 2 dpp-pair (v_mov+v_mov_dpp x2) + 4 v_pk_add_f32
// + 8 min3 (unsigned-bitcast -> v_min3_u32) + 8 fma + 1 ds_write_b64.
// Guard-free INFV=1e30 scheme as R7 (pads absorb OOB; junk sorts large).
//
// Output: b1/w3 (strip 7), lane 63, row 3 = global 2047, col jB = 2047
// at tau0 = 2112 (TAUMAX), s = 30.

#define NLEN   2048
#define NWL    4
#define CSTEP  64
#define SPB    (CSTEP / 2)
#define DSKEW  192
#define EXTRA  192
#define PAD    128
#define RROW   (PAD + 2176)            // ring cols -128..2175 -> 2304 floats
#define YPAD   128
#define TAUMAX 2112
#define GTOT   (TAUMAX + 7 * DSKEW + EXTRA + CSTEP)   // 3712
#define FLAGBIG (1 << 20)
#define INFV   1e30f

typedef float f32x2 __attribute__((ext_vector_type(2)));
typedef float f32x4 __attribute__((ext_vector_type(4)));

__device__ __forceinline__ float dpp_shr1(float v, float inj) {
    int r = __builtin_amdgcn_update_dpp(
        __builtin_bit_cast(int, inj), __builtin_bit_cast(int, v),
        0x138 /*wave_shr:1*/, 0xF, 0xF, false /*lane0 keeps old=inj*/);
    return __builtin_bit_cast(float, r);
}
// 3-input min on non-negative floats via unsigned bit-pattern compare;
// umin+umin fuses to a single v_min3_u32. NaN/inf/negative sort LARGE.
__device__ __forceinline__ float min3f(float a, float b, float c) {
    unsigned ia = __builtin_bit_cast(unsigned, a);
    unsigned ib = __builtin_bit_cast(unsigned, b);
    unsigned ic = __builtin_bit_cast(unsigned, c);
    unsigned m  = __builtin_elementwise_min(
                      __builtin_elementwise_min(ia, ib), ic);
    return __builtin_bit_cast(float, m);
}
// RELAXED spin (no buffer_inv); sched_barrier pins compiler ordering so
// data loads can't be hoisted above the observed flag value.
__device__ __forceinline__ int spinflag(int* flag, int target) {
    int f;
    while ((f = __hip_atomic_load(flag, __ATOMIC_RELAXED,
                                  __HIP_MEMORY_SCOPE_AGENT)) < target)
        __builtin_amdgcn_s_sleep(2);
    __builtin_amdgcn_sched_barrier(0);
    return f;
}
// Relaxed agent-scope atomic load/store: coherent point, bypass L2.
__device__ __forceinline__ float gload(const float* p) {
    unsigned u = __hip_atomic_load((const unsigned*)p, __ATOMIC_RELAXED,
                                   __HIP_MEMORY_SCOPE_AGENT);
    return __builtin_bit_cast(float, u);
}
__device__ __forceinline__ void gstore(float* p, float v) {
    __hip_atomic_store((unsigned*)p, __builtin_bit_cast(unsigned, v),
                       __ATOMIC_RELAXED, __HIP_MEMORY_SCOPE_AGENT);
}
__device__ __forceinline__ void fstore(int* p, int v) {
    __hip_atomic_store(p, v, __ATOMIC_RELAXED, __HIP_MEMORY_SCOPE_AGENT);
}

// ---------------- 2-block (2-CU) kernel ----------------
__global__ __launch_bounds__(256, 1) void dtw_kernel(const float* __restrict__ X,
                                                     const float* __restrict__ Y,
                                                     float* __restrict__ out,
                                                     float* __restrict__ ws) {
    int*   flag = (int*)ws;
    float* grow = ws + 16 + PAD;       // global ring base (col 0)

    __shared__ __align__(16) float yB[YPAD + NLEN + YPAD];
    __shared__ float ring[(NWL + 1) * RROW];
    __shared__ __align__(16) float cscr[CSTEP];   // consumer ring scratch
    float* yS = yB + YPAD;

    const int tid  = threadIdx.x;
    const int w    = tid >> 6;
    const int lane = tid & 63;
    const int b    = blockIdx.x;
    const int skew = (4 * b + w) * DSKEW + (b ? EXTRA : 0);
    const bool isprod = (b == 0) & (w == 3);
    const bool iscons = (b == 1) & (w == 0);

    {   // Y into LDS middle, INFV pads on both sides
        const float4* Y4 = (const float4*)Y;
        float4* y4 = (float4*)(yB + YPAD);
        y4[tid]       = Y4[tid];
        y4[tid + 256] = Y4[tid + 256];
        if (tid < YPAD) {
            yB[tid]               = INFV;
            yB[YPAD + NLEN + tid] = INFV;
        }
    }
    for (int k = tid; k < (NWL + 1) * RROW; k += 256) ring[k] = INFV;
    __syncthreads();

    f32x2 xx0, xx1, xx2, xx3;
    {   // strip rows: 256*(4b+w) + 4*lane
        const float4 xa = *(const float4*)&X[b * 1024 + w * 256 + lane * 4];
        xx0 = (f32x2){xa.x, xa.x}; xx1 = (f32x2){xa.y, xa.y};
        xx2 = (f32x2){xa.z, xa.z}; xx3 = (f32x2){xa.w, xa.w};
    }

    float pB0 = INFV, pB1 = INFV, pB2 = INFV, pB3 = INFV;
    float a3p = INFV;
    float uBp = (b == 0 && tid == 0) ? 0.0f : INFV;  // DTW[-1][-1]=0 seed
    float gnext = INFV;                              // consumer prefetch reg
    int   fc   = 0;                                  // cached flag value

    const float* ringR = ring + w * RROW + PAD;
    float*       ringW = ring + (w + 1) * RROW + PAD;

    for (int gb = 0; gb < GTOT; gb += CSTEP) {
        const int tau0 = gb - skew;

        // producer tail publish: round TAUMAX's stores are barrier-drained
        if (isprod && tau0 == TAUMAX + CSTEP && lane == 0)
            fstore(flag, FLAGBIG);

        if (tau0 >= 0 && tau0 <= TAUMAX) {
            // producer: deferred flag, covers stores of round tau0-64
            // (drained by the intervening __syncthreads vmcnt(0))
            if (isprod && tau0 >= 128 && lane == 0)
                fstore(flag, tau0 - 127);

            bool docp = false;                         // consumer cscr update?
            if (iscons) {
                if (tau0 == 0) {                       // prologue: first block
                    fc = spinflag(flag, 63);
                    cscr[lane] = gload(grow + lane);   // same-wave lgkm order
                }
                const int nt = tau0 + CSTEP;           // prefetch next block
                if (nt <= TAUMAX) {
                    int tgt = nt + 63;
                    if (tgt > NLEN - 1) tgt = NLEN - 1;
                    if (fc < tgt) fc = spinflag(flag, tgt);  // usually skipped
                    gnext = gload(grow + nt + lane);   // latency hidden
                    docp = true;
                }
            }

            // broadcast ring values: 64 cols in 16 uniform ds_read_b128
            // (wave-uniform address = conflict-free broadcast); per-step
            // extraction is a compile-time subregister pick = 0 VALU.
            const float* rsrc = iscons ? cscr : (ringR + tau0);
            f32x4 rv[16];
            #pragma unroll
            for (int q = 0; q < 16; ++q) rv[q] = *(const f32x4*)(rsrc + 4 * q);

            f32x2 y2[SPB];
            {
                const f32x2* yp = (const f32x2*)(yS + (tau0 - 2 * lane));
                #pragma unroll
                for (int k = 0; k < SPB; ++k) y2[k] = yp[k];
            }
            float* wp = ringW + (tau0 - 2 * lane);
            const bool isout = (b == 1) & (w == 3) & (lane == 63)
                             & (tau0 == TAUMAX);

            #pragma unroll
            for (int s = 0; s < SPB; ++s) {
                const float riA = rv[s >> 1][(2 * s) & 3];      // ring[tau0+2s]
                const float riB = rv[s >> 1][(2 * s + 1) & 3];  // ring[tau0+2s+1]
                const float uA  = dpp_shr1(a3p, riA);
                const float uB  = dpp_shr1(pB3, riB);
                const f32x2 yv = y2[s];
                f32x2 d0 = xx0 - yv;
                float n0A = fmaf(d0.x, d0.x, min3f(pB0, uA,  uBp));
                float n0B = fmaf(d0.y, d0.y, min3f(n0A, uB,  uA));
                f32x2 d1 = xx1 - yv;
                float n1A = fmaf(d1.x, d1.x, min3f(pB1, n0A, pB0));
                float n1B = fmaf(d1.y, d1.y, min3f(n1A, n0B, n0A));
                f32x2 d2 = xx2 - yv;
                float n2A = fmaf(d2.x, d2.x, min3f(pB2, n1A, pB1));
                float n2B = fmaf(d2.y, d2.y, min3f(n2A, n1B, n1A));
                f32x2 d3 = xx3 - yv;
                float n3A = fmaf(d3.x, d3.x, min3f(pB3, n2A, pB2));
                float n3B = fmaf(d3.y, d3.y, min3f(n3A, n2B, n2A));
                f32x2 wv; wv.x = n3A; wv.y = n3B;
                *(f32x2*)(wp + 2 * s) = wv;            // ds_write_b64
                uBp = uB; a3p = n3A;
                pB0 = n0B; pB1 = n1B; pB2 = n2B; pB3 = n3B;
                if (s == 30 && isout) out[0] = sqrtf(n3B);  // col 2047
            }

            if (isprod) {
                // newly-final cols -> coherent point (write-through
                // relaxed agent atomics; 256B; drained at the barrier)
                gstore(grow + (tau0 - 126 + lane), ringW[tau0 - 126 + lane]);
            }
            if (docp) cscr[lane] = gnext;              // park for next round
        }
        __syncthreads();
    }
}

// ---------------- fallback: R7 single-block kernel (proven 134.5us) ----------------
#define FNW    4
#define FGTOT  (TAUMAX + (FNW - 1) * DSKEW + CSTEP)   // 2752

__device__ __forceinline__ float rdlane(float v, int l) {
    return __builtin_bit_cast(float,
        __builtin_amdgcn_readlane(__builtin_bit_cast(int, v), l));
}

__global__ __launch_bounds__(256, 1) void dtw_kernel_fb(const float* __restrict__ X,
                                                        const float* __restrict__ Y,
                                                        float* __restrict__ out) {
    __shared__ __align__(16) float yB[YPAD + NLEN + YPAD];
    __shared__ float ring[(FNW + 1) * RROW];
    float* yS = yB + YPAD;

    const int tid  = threadIdx.x;
    const int w    = tid >> 6;
    const int lane = tid & 63;

    {
        const float4* Y4 = (const float4*)Y;
        float4* y4 = (float4*)(yB + YPAD);
        y4[tid]       = Y4[tid];
        y4[tid + 256] = Y4[tid + 256];
        if (tid < YPAD) {
            yB[tid]               = INFV;
            yB[YPAD + NLEN + tid] = INFV;
        }
    }
    for (int k = tid; k < (FNW + 1) * RROW; k += 256) ring[k] = INFV;
    __syncthreads();

    f32x2 xx0, xx1, xx2, xx3, xx4, xx5, xx6, xx7;
    {
        const float4 xa = *(const float4*)&X[tid * 8];
        const float4 xb = *(const float4*)&X[tid * 8 + 4];
        xx0 = (f32x2){xa.x, xa.x}; xx1 = (f32x2){xa.y, xa.y};
        xx2 = (f32x2){xa.z, xa.z}; xx3 = (f32x2){xa.w, xa.w};
        xx4 = (f32x2){xb.x, xb.x}; xx5 = (f32x2){xb.y, xb.y};
        xx6 = (f32x2){xb.z, xb.z}; xx7 = (f32x2){xb.w, xb.w};
    }

    float pB0 = INFV, pB1 = INFV, pB2 = INFV, pB3 = INFV;
    float pB4 = INFV, pB5 = INFV, pB6 = INFV, pB7 = INFV;
    float a7p = INFV;
    float uBp = (tid == 0) ? 0.0f : INFV;

    const float* ringR = ring + w * RROW + PAD;
    float*       ringW = ring + (w + 1) * RROW + PAD;

    for (int gb = 0; gb < FGTOT; gb += CSTEP) {
        const int tau0 = gb - w * DSKEW;

        if (tau0 >= 0 && tau0 <= TAUMAX) {
            const float rblk = ringR[tau0 + lane];
            f32x2 y2[SPB];
            {
                const f32x2* yp = (const f32x2*)(yS + (tau0 - 2 * lane));
                #pragma unroll
                for (int k = 0; k < SPB; ++k) y2[k] = yp[k];
            }
            float* wp = ringW + (tau0 - 2 * lane);
            const bool isout = (tau0 == TAUMAX) & (w == FNW - 1) & (lane == 63);

            #pragma unroll
            for (int s = 0; s < SPB; ++s) {
                const float riA = rdlane(rblk, 2 * s);
                const float riB = rdlane(rblk, 2 * s + 1);
                const float uA  = dpp_shr1(a7p, riA);
                const float uB  = dpp_shr1(pB7, riB);
                const f32x2 yv = y2[s];
                f32x2 d0 = xx0 - yv;
                float n0A = fmaf(d0.x, d0.x, min3f(pB0, uA,  uBp));
                float n0B = fmaf(d0.y, d0.y, min3f(n0A, uB,  uA));
                f32x2 d1 = xx1 - yv;
                float n1A = fmaf(d1.x, d1.x, min3f(pB1, n0A, pB0));
                float n1B = fmaf(d1.y, d1.y, min3f(n1A, n0B, n0A));
                f32x2 d2 = xx2 - yv;
                float n2A = fmaf(d2.x, d2.x, min3f(pB2, n1A, pB1));
                float n2B = fmaf(d2.y, d2.y, min3f(n2A, n1B, n1A));
                f32x2 d3 = xx3 - yv;
                float n3A = fmaf(d3.x, d3.x, min3f(pB3, n2A, pB2));
                float n3B = fmaf(d3.y, d3.y, min3f(n3A, n2B, n2A));
                f32x2 d4 = xx4 - yv;
                float n4A = fmaf(d4.x, d4.x, min3f(pB4, n3A, pB3));
                float n4B = fmaf(d4.y, d4.y, min3f(n4A, n3B, n3A));
                f32x2 d5 = xx5 - yv;
                float n5A = fmaf(d5.x, d5.x, min3f(pB5, n4A, pB4));
                float n5B = fmaf(d5.y, d5.y, min3f(n5A, n4B, n4A));
                f32x2 d6 = xx6 - yv;
                float n6A = fmaf(d6.x, d6.x, min3f(pB6, n5A, pB5));
                float n6B = fmaf(d6.y, d6.y, min3f(n6A, n5B, n5A));
                f32x2 d7 = xx7 - yv;
                float n7A = fmaf(d7.x, d7.x, min3f(pB7, n6A, pB6));
                float n7B = fmaf(d7.y, d7.y, min3f(n7A, n6B, n6A));
                f32x2 wv; wv.x = n7A; wv.y = n7B;
                *(f32x2*)(wp + 2 * s) = wv;
                uBp = uB; a7p = n7A;
                pB0 = n0B; pB1 = n1B; pB2 = n2B; pB3 = n3B;
                pB4 = n4B; pB5 = n5B; pB6 = n6B; pB7 = n7B;
                if (s == 30 && isout) out[0] = sqrtf(n7B);
            }
        }
        __syncthreads();
    }
}

extern "C" void kernel_launch(void* const* d_in, const int* in_sizes, int n_in,
                              void* d_out, int out_size, void* d_ws, size_t ws_size,
                              hipStream_t stream) {
    const float* x = (const float*)d_in[0];
    const float* y = (const float*)d_in[1];
    (void)in_sizes; (void)n_in; (void)out_size;
    if (d_ws != nullptr && ws_size >= 16384) {
        hipMemsetAsync(d_ws, 0, 4, stream);          // zero the flag
        dtw_kernel<<<2, 256, 0, stream>>>(x, y, (float*)d_out, (float*)d_ws);
    } else {
        dtw_kernel_fb<<<1, 256, 0, stream>>>(x, y, (float*)d_out);
    }
}